// Round 1
// baseline (2782.005 us; speedup 1.0000x reference)
//
#include <hip/hip_runtime.h>
#include <hip/hip_bf16.h>
#include <math.h>

// Problem constants (from reference setup_inputs)
constexpr int BATCH = 2;
constexpr int SEQLEN = 4096;
constexpr int NH = 16;     // heads
constexpr int DS = 64;     // d_state
constexpr int DH = 64;     // d_head

// ---------------------------------------------------------------------------
// Kernel 1: alpha precompute.
// Key algebra: pred_err = (1-ad)^2 * xbar^2 * mean_s(B[s]^2)  (state-independent)
// 16 lanes cooperate per (b,t,h) row: coalesced float4 loads + shfl reduce.
// ---------------------------------------------------------------------------
__global__ __launch_bounds__(256) void alpha_kernel(
    const float* __restrict__ X, const float* __restrict__ A,
    const float* __restrict__ Bm,
    const float* __restrict__ l2ab, const float* __restrict__ l2b,
    const float* __restrict__ sema,
    float* __restrict__ alpha_out, int total /* BATCH*L*H */, int H) {
  int tid  = blockIdx.x * 256 + threadIdx.x;
  int item = tid >> 4;   // 16 lanes per (b,t,h) item
  int sub  = tid & 15;
  if (item >= total) return;

  const float4 xv = *(const float4*)(X  + (size_t)item * 64 + sub * 4);
  const float4 bv = *(const float4*)(Bm + (size_t)item * 64 + sub * 4);
  float sx = xv.x + xv.y + xv.z + xv.w;
  float sb = bv.x * bv.x + bv.y * bv.y + bv.z * bv.z + bv.w * bv.w;
  // reduce over the 16-lane group (stays inside the wave)
  #pragma unroll
  for (int m = 1; m < 16; m <<= 1) {
    sx += __shfl_xor(sx, m, 64);
    sb += __shfl_xor(sb, m, 64);
  }
  if (sub == 0) {
    int h = item % H;
    float xbar = sx * (1.0f / 64.0f);
    float bsq  = sb * (1.0f / 64.0f);
    float ad   = expf(A[item]);
    float lab  = fminf(fmaxf(l2ab[h], -3.32f), -0.015f);
    float ab   = 1.0f - exp2f(lab);
    float lb   = fminf(fmaxf(l2b[h], -2.0f), 2.0f);
    float beta = exp2f(lb);
    float ema  = sema[h] + 1e-6f;
    float om   = 1.0f - ad;
    float pe   = om * om * xbar * xbar * bsq;
    float ns   = pe / ema;
    float boost = fmaxf(tanhf(beta * ns), 0.0f);
    float al   = ab + (1.0f - ab) * boost;
    al = fminf(fmaxf(al, 0.01f), 0.999f);
    alpha_out[item] = al;
  }
}

// ---------------------------------------------------------------------------
// Kernel 2: sequential scan. One block (256 thr) per (b,h) chain; 32 blocks.
// State h[s][d] (64x64) in registers: lane d = tid&63, wave w = tid>>6 owns
// s = w*16..w*16+15 (16 f32 regs/thread).
// Per step: h = al*h + (1-al)*B[s]*x[d];  y[d] = sum_s C[s]*h[s][d]
// Double-buffered LDS staging (loads issued 1 step ahead), double-buffered
// reduction scratch -> single __syncthreads per step.
// ---------------------------------------------------------------------------
__global__ __launch_bounds__(256) void scan_kernel(
    const float* __restrict__ X, const float* __restrict__ Bm,
    const float* __restrict__ Cm, const float* __restrict__ alpha_in,
    float* __restrict__ Y, int L, int H) {
  int bh = blockIdx.x;           // b*H + h
  int b = bh / H, h = bh % H;
  int tid = threadIdx.x;
  int d = tid & 63;
  int w = tid >> 6;              // 0..3

  const size_t rowstride = (size_t)H * 64;              // floats between t's
  const size_t base  = ((size_t)b * L * H + h) * 64;    // t=0 row offset
  const size_t abase = (size_t)b * L * H + h;           // alpha idx, stride H

  __shared__ float xb[2][64], bb[2][64], cb[2][64], ab_s[2];
  __shared__ float red[2][4][64];

  float hreg[16];
  #pragma unroll
  for (int k = 0; k < 16; ++k) hreg[k] = 0.0f;

  // prologue: stage t=0 into buffer 0
  if (w == 0)      xb[0][d] = X[base + d];
  else if (w == 1) bb[0][d] = Bm[base + d];
  else if (w == 2) cb[0][d] = Cm[base + d];
  else if (d == 0) ab_s[0]  = alpha_in[abase];
  __syncthreads();

  for (int t = 0; t < L; ++t) {
    const int cur = t & 1, nxt = cur ^ 1;

    // issue next-step global loads early (latency hidden under compute)
    float regn = 0.0f;
    if (t + 1 < L) {
      size_t off = base + (size_t)(t + 1) * rowstride + d;
      if (w == 0)      regn = X[off];
      else if (w == 1) regn = Bm[off];
      else if (w == 2) regn = Cm[off];
      else if (d == 0) regn = alpha_in[abase + (size_t)(t + 1) * H];
    }

    // compute step t from current buffers
    float al = ab_s[cur];
    float xv = xb[cur][d];
    float t1 = (1.0f - al) * xv;
    float p = 0.0f;
    const float4* bp = (const float4*)&bb[cur][w * 16];
    const float4* cp = (const float4*)&cb[cur][w * 16];
    #pragma unroll
    for (int k4 = 0; k4 < 4; ++k4) {
      float4 b4 = bp[k4];
      float4 c4 = cp[k4];
      hreg[k4*4+0] = al * hreg[k4*4+0] + b4.x * t1;  p += c4.x * hreg[k4*4+0];
      hreg[k4*4+1] = al * hreg[k4*4+1] + b4.y * t1;  p += c4.y * hreg[k4*4+1];
      hreg[k4*4+2] = al * hreg[k4*4+2] + b4.z * t1;  p += c4.z * hreg[k4*4+2];
      hreg[k4*4+3] = al * hreg[k4*4+3] + b4.w * t1;  p += c4.w * hreg[k4*4+3];
    }
    red[cur][w][d] = p;

    // stage next-step data into the other buffer
    if (t + 1 < L) {
      if (w == 0)      xb[nxt][d] = regn;
      else if (w == 1) bb[nxt][d] = regn;
      else if (w == 2) cb[nxt][d] = regn;
      else if (d == 0) ab_s[nxt]  = regn;
    }

    __syncthreads();

    // wave 0 folds the 4 partials and stores y_t (other waves run ahead;
    // they write red[nxt] next iter, so no race on red[cur])
    if (w == 0) {
      float y = red[cur][0][d] + red[cur][1][d] + red[cur][2][d] + red[cur][3][d];
      Y[base + (size_t)t * rowstride + d] = y;
    }
  }
}

extern "C" void kernel_launch(void* const* d_in, const int* in_sizes, int n_in,
                              void* d_out, int out_size, void* d_ws, size_t ws_size,
                              hipStream_t stream) {
  const float* X    = (const float*)d_in[0];
  const float* A    = (const float*)d_in[1];
  const float* Bm   = (const float*)d_in[2];
  const float* Cm   = (const float*)d_in[3];
  const float* l2ab = (const float*)d_in[4];
  const float* l2b  = (const float*)d_in[5];
  const float* sema = (const float*)d_in[6];
  float* Y = (float*)d_out;
  float* alpha_ws = (float*)d_ws;  // BATCH*L*H floats = 512 KB

  const int total = BATCH * SEQLEN * NH;          // 131072
  const int ablocks = (total * 16) / 256;         // 16 lanes/item
  alpha_kernel<<<ablocks, 256, 0, stream>>>(X, A, Bm, l2ab, l2b, sema,
                                            alpha_ws, total, NH);
  scan_kernel<<<BATCH * NH, 256, 0, stream>>>(X, Bm, Cm, alpha_ws, Y,
                                              SEQLEN, NH);
}

// Round 2
// 106.935 us; speedup vs baseline: 26.0160x; 26.0160x over previous
//
#include <hip/hip_runtime.h>
#include <hip/hip_bf16.h>
#include <math.h>

constexpr int BATCH = 2, L = 4096, NH = 16;
constexpr int T = 64;              // chunk length
constexpr int NC = L / T;          // 64 chunks
constexpr int BH = BATCH * NH;     // 32 chains
constexpr int PAD = 68;            // padded LDS row (floats), keeps 16B align

// ws layout (floats)
constexpr size_t S_OFF    = 0;                                  // [BH][NC][64*64]
constexpr size_t LAM_OFF  = (size_t)BH * NC * 64 * 64;          // [BH][NC]
constexpr size_t CLS_OFF  = LAM_OFF + (size_t)BH * NC;          // [BH][NC][T]
constexpr size_t ONEM_OFF = CLS_OFF + (size_t)BH * NC * T;      // [BH][NC][T]
constexpr size_t WS_FLOATS = ONEM_OFF + (size_t)BH * NC * T;

__device__ __forceinline__ float alpha_formula(float Aval, float xbar, float bsq,
                                               float lab_c, float beta, float ema) {
  float ad = expf(Aval);
  float ab = 1.f - exp2f(lab_c);
  float om = 1.f - ad;
  float ns = om * om * xbar * xbar * bsq / ema;
  float boost = fmaxf(tanhf(beta * ns), 0.f);
  return fminf(fmaxf(ab + (1.f - ab) * boost, 0.01f), 0.999f);
}

// ---------------------------------------------------------------------------
// Phase 1: per (bh, chunk): alpha/cls/coeff, S_c = B~^T X, Lambda_c
// ---------------------------------------------------------------------------
__global__ __launch_bounds__(256) void phase1(
    const float* __restrict__ X, const float* __restrict__ A,
    const float* __restrict__ Bm,
    const float* __restrict__ l2ab, const float* __restrict__ l2b,
    const float* __restrict__ sema, float* __restrict__ ws) {
  const int bid = blockIdx.x;                 // bh*NC + c
  const int bh = bid >> 6, c = bid & 63;
  const int b = bh >> 4, h = bh & 15;
  const int tid = threadIdx.x;

  __shared__ float Xl[T][PAD], Bl[T][PAD];
  __shared__ float xb_s[T], bq_s[T], coeff_s[T];

  const size_t g0 = ((size_t)(b * L + c * T) * NH + h) * 64;
  const int r = tid >> 2, q = tid & 3;
  const size_t grow = g0 + (size_t)r * (NH * 64);
  #pragma unroll
  for (int i = 0; i < 4; ++i) {
    int col = q * 16 + i * 4;
    *(float4*)&Xl[r][col] = *(const float4*)(X + grow + col);
    *(float4*)&Bl[r][col] = *(const float4*)(Bm + grow + col);
  }
  __syncthreads();

  float sx = 0.f, sb = 0.f;
  #pragma unroll
  for (int i = 0; i < 4; ++i) {
    float4 xv = *(const float4*)&Xl[r][q * 16 + i * 4];
    float4 bv = *(const float4*)&Bl[r][q * 16 + i * 4];
    sx += xv.x + xv.y + xv.z + xv.w;
    sb += bv.x * bv.x + bv.y * bv.y + bv.z * bv.z + bv.w * bv.w;
  }
  sx += __shfl_xor(sx, 1, 64); sx += __shfl_xor(sx, 2, 64);
  sb += __shfl_xor(sb, 1, 64); sb += __shfl_xor(sb, 2, 64);
  if (q == 0) { xb_s[r] = sx * (1.f / 64.f); bq_s[r] = sb * (1.f / 64.f); }
  __syncthreads();

  if (tid < 64) {
    float lab_c = fminf(fmaxf(l2ab[h], -3.32f), -0.015f);
    float beta  = exp2f(fminf(fmaxf(l2b[h], -2.f), 2.f));
    float ema   = sema[h] + 1e-6f;
    float Aval  = A[(size_t)(b * L + c * T + tid) * NH + h];
    float al = alpha_formula(Aval, xb_s[tid], bq_s[tid], lab_c, beta, ema);
    float onem = 1.f - al;
    float cls = logf(al);
    #pragma unroll
    for (int off = 1; off < 64; off <<= 1) {
      float o = __shfl_up(cls, off, 64);
      if (tid >= off) cls += o;
    }
    float cls63 = __shfl(cls, 63, 64);
    coeff_s[tid] = expf(cls63 - cls) * onem;
    size_t cb = (size_t)bid * T;
    ws[CLS_OFF + cb + tid]  = cls;
    ws[ONEM_OFF + cb + tid] = onem;
    if (tid == 63) ws[LAM_OFF + bid] = expf(cls63);
  }
  __syncthreads();

  const int s0 = (tid >> 4) * 4, d0 = (tid & 15) * 4;
  float acc[4][4] = {};
  #pragma unroll 4
  for (int j = 0; j < 64; ++j) {
    float w = coeff_s[j];
    float4 bv = *(const float4*)&Bl[j][s0];
    float4 xv = *(const float4*)&Xl[j][d0];
    float bb[4] = {bv.x * w, bv.y * w, bv.z * w, bv.w * w};
    float xx[4] = {xv.x, xv.y, xv.z, xv.w};
    #pragma unroll
    for (int k = 0; k < 4; ++k)
      #pragma unroll
      for (int l = 0; l < 4; ++l)
        acc[k][l] += bb[k] * xx[l];
  }
  float* Sp = ws + S_OFF + (size_t)bid * 4096;
  #pragma unroll
  for (int k = 0; k < 4; ++k) {
    float4 v = {acc[k][0], acc[k][1], acc[k][2], acc[k][3]};
    *(float4*)(Sp + (size_t)(s0 + k) * 64 + d0) = v;
  }
}

// ---------------------------------------------------------------------------
// Phase 2: elementwise scan over chunks; in-place S -> h0 (state at chunk start)
// ---------------------------------------------------------------------------
__global__ __launch_bounds__(256) void phase2(float* __restrict__ ws) {
  const int gtid = blockIdx.x * 256 + threadIdx.x;
  const int bh = gtid >> 12, sd = gtid & 4095;
  const float* lam = ws + LAM_OFF + (size_t)bh * NC;
  float* S = ws + S_OFF;
  const size_t base = (size_t)bh * NC * 4096 + sd;
  float hv = 0.f;
  #pragma unroll 4
  for (int c = 0; c < NC; ++c) {
    size_t off = base + (size_t)c * 4096;
    float v = S[off];
    S[off] = hv;
    hv = lam[c] * hv + v;
  }
}

// ---------------------------------------------------------------------------
// Phase 3: per (bh, chunk): Y = diag(e^cls) C h0 + (W ⊙ (C B^T)) X
// ---------------------------------------------------------------------------
__global__ __launch_bounds__(256) void phase3(
    const float* __restrict__ X, const float* __restrict__ Bm,
    const float* __restrict__ Cm, const float* __restrict__ ws,
    float* __restrict__ Y) {
  const int bid = blockIdx.x;
  const int bh = bid >> 6, c = bid & 63;
  const int b = bh >> 4, h = bh & 15;
  const int tid = threadIdx.x;

  __shared__ float Xl[T][64];   // [j][d]
  __shared__ float Ct[T][64];   // [s][t]; later WGt[j][t]
  __shared__ float Hb[T][64];   // h0[s][d]; later Bt[s][j]
  __shared__ float cls_s[T], onem_s[T];

  const size_t g0 = ((size_t)(b * L + c * T) * NH + h) * 64;
  const int r = tid >> 2, q = tid & 3;
  const size_t grow = g0 + (size_t)r * (NH * 64);
  const float* h0p = ws + S_OFF + (size_t)bid * 4096;
  #pragma unroll
  for (int i = 0; i < 4; ++i) {
    int col = q * 16 + i * 4;
    *(float4*)&Xl[r][col] = *(const float4*)(X + grow + col);
    float4 cv = *(const float4*)(Cm + grow + col);
    Ct[col + 0][r] = cv.x; Ct[col + 1][r] = cv.y;
    Ct[col + 2][r] = cv.z; Ct[col + 3][r] = cv.w;
    *(float4*)&Hb[r][col] = *(const float4*)(h0p + (size_t)r * 64 + col);
  }
  if (tid < 64) {
    cls_s[tid]  = ws[CLS_OFF + (size_t)bid * T + tid];
    onem_s[tid] = ws[ONEM_OFF + (size_t)bid * T + tid];
  }
  __syncthreads();

  const int t0 = (tid >> 4) * 4;   // t block
  const int u0 = (tid & 15) * 4;   // d (or j) block

  // Yacc = e^{cls_t} * (C @ h0)
  float yacc[4][4] = {};
  #pragma unroll 4
  for (int s = 0; s < 64; ++s) {
    float4 cv = *(const float4*)&Ct[s][t0];
    float4 hv = *(const float4*)&Hb[s][u0];
    float cc[4] = {cv.x, cv.y, cv.z, cv.w};
    float hh[4] = {hv.x, hv.y, hv.z, hv.w};
    #pragma unroll
    for (int k = 0; k < 4; ++k)
      #pragma unroll
      for (int l = 0; l < 4; ++l)
        yacc[k][l] += cc[k] * hh[l];
  }
  #pragma unroll
  for (int k = 0; k < 4; ++k) {
    float ce = expf(cls_s[t0 + k]);
    #pragma unroll
    for (int l = 0; l < 4; ++l) yacc[k][l] *= ce;
  }
  __syncthreads();   // all h0 reads done

  // restage B transposed into Hb
  #pragma unroll
  for (int i = 0; i < 4; ++i) {
    int col = q * 16 + i * 4;
    float4 bv = *(const float4*)(Bm + grow + col);
    Hb[col + 0][r] = bv.x; Hb[col + 1][r] = bv.y;
    Hb[col + 2][r] = bv.z; Hb[col + 3][r] = bv.w;
  }
  __syncthreads();

  // G = C B^T, then weight+mask
  float wg[4][4] = {};
  #pragma unroll 4
  for (int s = 0; s < 64; ++s) {
    float4 cv = *(const float4*)&Ct[s][t0];
    float4 bv = *(const float4*)&Hb[s][u0];
    float cc[4] = {cv.x, cv.y, cv.z, cv.w};
    float bb[4] = {bv.x, bv.y, bv.z, bv.w};
    #pragma unroll
    for (int k = 0; k < 4; ++k)
      #pragma unroll
      for (int l = 0; l < 4; ++l)
        wg[k][l] += cc[k] * bb[l];
  }
  #pragma unroll
  for (int k = 0; k < 4; ++k)
    #pragma unroll
    for (int l = 0; l < 4; ++l) {
      int t = t0 + k, j = u0 + l;
      float w = (t >= j) ? expf(cls_s[t] - cls_s[j]) * onem_s[j] : 0.f;
      wg[k][l] *= w;
    }
  __syncthreads();   // all Ct reads done

  #pragma unroll
  for (int k = 0; k < 4; ++k)
    #pragma unroll
    for (int l = 0; l < 4; ++l)
      Ct[u0 + l][t0 + k] = wg[k][l];   // WGt[j][t]
  __syncthreads();

  // Y += WG @ X
  #pragma unroll 4
  for (int j = 0; j < 64; ++j) {
    float4 wv = *(const float4*)&Ct[j][t0];
    float4 xv = *(const float4*)&Xl[j][u0];
    float ww[4] = {wv.x, wv.y, wv.z, wv.w};
    float xx[4] = {xv.x, xv.y, xv.z, xv.w};
    #pragma unroll
    for (int k = 0; k < 4; ++k)
      #pragma unroll
      for (int l = 0; l < 4; ++l)
        yacc[k][l] += ww[k] * xx[l];
  }
  #pragma unroll
  for (int k = 0; k < 4; ++k) {
    float4 v = {yacc[k][0], yacc[k][1], yacc[k][2], yacc[k][3]};
    *(float4*)(Y + g0 + (size_t)(t0 + k) * (NH * 64) + u0) = v;
  }
}

// ---------------------------------------------------------------------------
// Fallback (round-1) path if ws is too small
// ---------------------------------------------------------------------------
__global__ __launch_bounds__(256) void alpha_kernel(
    const float* __restrict__ X, const float* __restrict__ A,
    const float* __restrict__ Bm,
    const float* __restrict__ l2ab, const float* __restrict__ l2b,
    const float* __restrict__ sema,
    float* __restrict__ alpha_out, int total, int H) {
  int tid = blockIdx.x * 256 + threadIdx.x;
  int item = tid >> 4, sub = tid & 15;
  if (item >= total) return;
  const float4 xv = *(const float4*)(X + (size_t)item * 64 + sub * 4);
  const float4 bv = *(const float4*)(Bm + (size_t)item * 64 + sub * 4);
  float sx = xv.x + xv.y + xv.z + xv.w;
  float sb = bv.x * bv.x + bv.y * bv.y + bv.z * bv.z + bv.w * bv.w;
  #pragma unroll
  for (int m = 1; m < 16; m <<= 1) {
    sx += __shfl_xor(sx, m, 64);
    sb += __shfl_xor(sb, m, 64);
  }
  if (sub == 0) {
    int h = item % H;
    float lab_c = fminf(fmaxf(l2ab[h], -3.32f), -0.015f);
    float beta  = exp2f(fminf(fmaxf(l2b[h], -2.f), 2.f));
    float ema   = sema[h] + 1e-6f;
    alpha_out[item] = alpha_formula(A[item], sx * (1.f/64.f), sb * (1.f/64.f),
                                    lab_c, beta, ema);
  }
}

__global__ __launch_bounds__(256) void scan_kernel(
    const float* __restrict__ X, const float* __restrict__ Bm,
    const float* __restrict__ Cm, const float* __restrict__ alpha_in,
    float* __restrict__ Y, int Ln, int H) {
  int bh = blockIdx.x;
  int b = bh / H, h = bh % H;
  int tid = threadIdx.x;
  int d = tid & 63, w = tid >> 6;
  const size_t rowstride = (size_t)H * 64;
  const size_t base = ((size_t)b * Ln * H + h) * 64;
  const size_t abase = (size_t)b * Ln * H + h;
  __shared__ float xb[2][64], bb2[2][64], cb[2][64], ab_s[2];
  __shared__ float red[2][4][64];
  float hreg[16];
  #pragma unroll
  for (int k = 0; k < 16; ++k) hreg[k] = 0.0f;
  if (w == 0)      xb[0][d]  = X[base + d];
  else if (w == 1) bb2[0][d] = Bm[base + d];
  else if (w == 2) cb[0][d]  = Cm[base + d];
  else if (d == 0) ab_s[0]   = alpha_in[abase];
  __syncthreads();
  for (int t = 0; t < Ln; ++t) {
    const int cur = t & 1, nxt = cur ^ 1;
    float regn = 0.0f;
    if (t + 1 < Ln) {
      size_t off = base + (size_t)(t + 1) * rowstride + d;
      if (w == 0)      regn = X[off];
      else if (w == 1) regn = Bm[off];
      else if (w == 2) regn = Cm[off];
      else if (d == 0) regn = alpha_in[abase + (size_t)(t + 1) * H];
    }
    float al = ab_s[cur];
    float xv = xb[cur][d];
    float t1 = (1.0f - al) * xv;
    float p = 0.0f;
    const float4* bp = (const float4*)&bb2[cur][w * 16];
    const float4* cp = (const float4*)&cb[cur][w * 16];
    #pragma unroll
    for (int k4 = 0; k4 < 4; ++k4) {
      float4 b4 = bp[k4]; float4 c4 = cp[k4];
      hreg[k4*4+0] = al * hreg[k4*4+0] + b4.x * t1;  p += c4.x * hreg[k4*4+0];
      hreg[k4*4+1] = al * hreg[k4*4+1] + b4.y * t1;  p += c4.y * hreg[k4*4+1];
      hreg[k4*4+2] = al * hreg[k4*4+2] + b4.z * t1;  p += c4.z * hreg[k4*4+2];
      hreg[k4*4+3] = al * hreg[k4*4+3] + b4.w * t1;  p += c4.w * hreg[k4*4+3];
    }
    red[cur][w][d] = p;
    if (t + 1 < Ln) {
      if (w == 0)      xb[nxt][d]  = regn;
      else if (w == 1) bb2[nxt][d] = regn;
      else if (w == 2) cb[nxt][d]  = regn;
      else if (d == 0) ab_s[nxt]   = regn;
    }
    __syncthreads();
    if (w == 0) {
      float y = red[cur][0][d] + red[cur][1][d] + red[cur][2][d] + red[cur][3][d];
      Y[base + (size_t)t * rowstride + d] = y;
    }
  }
}

extern "C" void kernel_launch(void* const* d_in, const int* in_sizes, int n_in,
                              void* d_out, int out_size, void* d_ws, size_t ws_size,
                              hipStream_t stream) {
  const float* X    = (const float*)d_in[0];
  const float* A    = (const float*)d_in[1];
  const float* Bm   = (const float*)d_in[2];
  const float* Cm   = (const float*)d_in[3];
  const float* l2ab = (const float*)d_in[4];
  const float* l2b  = (const float*)d_in[5];
  const float* sema = (const float*)d_in[6];
  float* Y = (float*)d_out;
  float* ws = (float*)d_ws;

  if (ws_size >= WS_FLOATS * sizeof(float)) {
    phase1<<<BH * NC, 256, 0, stream>>>(X, A, Bm, l2ab, l2b, sema, ws);
    phase2<<<(BH * 4096) / 256, 256, 0, stream>>>(ws);
    phase3<<<BH * NC, 256, 0, stream>>>(X, Bm, Cm, ws, Y);
  } else {
    const int total = BATCH * L * NH;
    alpha_kernel<<<(total * 16) / 256, 256, 0, stream>>>(X, A, Bm, l2ab, l2b,
                                                         sema, ws, total, NH);
    scan_kernel<<<BH, 256, 0, stream>>>(X, Bm, Cm, ws, Y, L, NH);
  }
}

// Round 3
// 75.690 us; speedup vs baseline: 36.7554x; 1.4128x over previous
//
#include <hip/hip_runtime.h>
#include <hip/hip_bf16.h>
#include <math.h>

constexpr int BATCH = 2, L = 4096, NH = 16;
constexpr int T = 64;              // chunk length
constexpr int NC = L / T;          // 64 chunks
constexpr int BH = BATCH * NH;     // 32 chains
constexpr int PAD = 68;            // padded LDS row (floats) for phase1

// ws layout (floats)
constexpr size_t S_OFF    = 0;                                  // [BH][NC][64*64]  (S^T: [d][s])
constexpr size_t LAM_OFF  = (size_t)BH * NC * 64 * 64;          // [BH][NC]
constexpr size_t CLS_OFF  = LAM_OFF + (size_t)BH * NC;          // [BH][NC][T]
constexpr size_t ONEM_OFF = CLS_OFF + (size_t)BH * NC * T;      // [BH][NC][T]
constexpr size_t WS_FLOATS = ONEM_OFF + (size_t)BH * NC * T;

typedef __attribute__((ext_vector_type(8))) short short8;
typedef __attribute__((ext_vector_type(4))) float f32x4;

__device__ __forceinline__ unsigned short f2bf(float f) {
  union { float f; unsigned u; } v; v.f = f;
  unsigned r = v.u + 0x7FFFu + ((v.u >> 16) & 1u);   // RTNE
  return (unsigned short)(r >> 16);
}

// swizzled u16 index into a [64][64] bf16 LDS tile (16B-granular XOR swizzle)
__device__ __forceinline__ int swz(int row, int col) {
  return row * 64 + (col ^ ((row & 7) << 3));
}

__device__ __forceinline__ float alpha_formula(float Aval, float xbar, float bsq,
                                               float lab_c, float beta, float ema) {
  float ad = expf(Aval);
  float ab = 1.f - exp2f(lab_c);
  float om = 1.f - ad;
  float ns = om * om * xbar * xbar * bsq / ema;
  float boost = fmaxf(tanhf(beta * ns), 0.f);
  return fminf(fmaxf(ab + (1.f - ab) * boost, 0.01f), 0.999f);
}

// ---------------------------------------------------------------------------
// Phase 1: per (bh, chunk): alpha/cls/coeff, S^T_c = (X^T diag(coeff) B), lam
// ---------------------------------------------------------------------------
__global__ __launch_bounds__(256) void phase1(
    const float* __restrict__ X, const float* __restrict__ A,
    const float* __restrict__ Bm,
    const float* __restrict__ l2ab, const float* __restrict__ l2b,
    const float* __restrict__ sema, float* __restrict__ ws) {
  const int bid = blockIdx.x;                 // bh*NC + c
  const int bh = bid >> 6, c = bid & 63;
  const int b = bh >> 4, h = bh & 15;
  const int tid = threadIdx.x;

  __shared__ float Xl[T][PAD], Bl[T][PAD];
  __shared__ float xb_s[T], bq_s[T], coeff_s[T];

  const size_t g0 = ((size_t)(b * L + c * T) * NH + h) * 64;
  const int r = tid >> 2, q = tid & 3;
  const size_t grow = g0 + (size_t)r * (NH * 64);
  #pragma unroll
  for (int i = 0; i < 4; ++i) {
    int col = q * 16 + i * 4;
    *(float4*)&Xl[r][col] = *(const float4*)(X + grow + col);
    *(float4*)&Bl[r][col] = *(const float4*)(Bm + grow + col);
  }
  __syncthreads();

  float sx = 0.f, sb = 0.f;
  #pragma unroll
  for (int i = 0; i < 4; ++i) {
    float4 xv = *(const float4*)&Xl[r][q * 16 + i * 4];
    float4 bv = *(const float4*)&Bl[r][q * 16 + i * 4];
    sx += xv.x + xv.y + xv.z + xv.w;
    sb += bv.x * bv.x + bv.y * bv.y + bv.z * bv.z + bv.w * bv.w;
  }
  sx += __shfl_xor(sx, 1, 64); sx += __shfl_xor(sx, 2, 64);
  sb += __shfl_xor(sb, 1, 64); sb += __shfl_xor(sb, 2, 64);
  if (q == 0) { xb_s[r] = sx * (1.f / 64.f); bq_s[r] = sb * (1.f / 64.f); }
  __syncthreads();

  if (tid < 64) {
    float lab_c = fminf(fmaxf(l2ab[h], -3.32f), -0.015f);
    float beta  = exp2f(fminf(fmaxf(l2b[h], -2.f), 2.f));
    float ema   = sema[h] + 1e-6f;
    float Aval  = A[(size_t)(b * L + c * T + tid) * NH + h];
    float al = alpha_formula(Aval, xb_s[tid], bq_s[tid], lab_c, beta, ema);
    float onem = 1.f - al;
    float cls = logf(al);
    #pragma unroll
    for (int off = 1; off < 64; off <<= 1) {
      float o = __shfl_up(cls, off, 64);
      if (tid >= off) cls += o;
    }
    float cls63 = __shfl(cls, 63, 64);
    coeff_s[tid] = expf(cls63 - cls) * onem;
    size_t cb = (size_t)bid * T;
    ws[CLS_OFF + cb + tid]  = cls;
    ws[ONEM_OFF + cb + tid] = onem;
    if (tid == 63) ws[LAM_OFF + bid] = expf(cls63);
  }
  __syncthreads();

  // S^T[d][s] = sum_j coeff[j] * X[j][d] * B[j][s]
  const int u0 = (tid >> 4) * 4;   // d-block
  const int v0 = (tid & 15) * 4;   // s-block
  float acc[4][4] = {};
  #pragma unroll 4
  for (int j = 0; j < 64; ++j) {
    float w = coeff_s[j];
    float4 xv = *(const float4*)&Xl[j][u0];
    float4 bv = *(const float4*)&Bl[j][v0];
    float xx[4] = {xv.x, xv.y, xv.z, xv.w};
    float bb[4] = {bv.x * w, bv.y * w, bv.z * w, bv.w * w};
    #pragma unroll
    for (int k = 0; k < 4; ++k)
      #pragma unroll
      for (int l = 0; l < 4; ++l)
        acc[k][l] += xx[k] * bb[l];
  }
  float* Sp = ws + S_OFF + (size_t)bid * 4096;
  #pragma unroll
  for (int k = 0; k < 4; ++k) {
    float4 v = {acc[k][0], acc[k][1], acc[k][2], acc[k][3]};
    *(float4*)(Sp + (size_t)(u0 + k) * 64 + v0) = v;
  }
}

// ---------------------------------------------------------------------------
// Phase 2: elementwise exclusive scan over chunks (in-place, float4-vectorized)
// S layout is [d][s] but the scan is layout-agnostic.
// ---------------------------------------------------------------------------
__global__ __launch_bounds__(256) void phase2(float* __restrict__ ws) {
  const int gtid = blockIdx.x * 256 + threadIdx.x;   // BH*1024 threads
  const int bh = gtid >> 10;
  const int sd4 = (gtid & 1023) * 4;
  const float* lam = ws + LAM_OFF + (size_t)bh * NC;
  float* S = ws + S_OFF;
  const size_t base = (size_t)bh * NC * 4096 + sd4;
  float4 hv = {0.f, 0.f, 0.f, 0.f};
  #pragma unroll 4
  for (int c = 0; c < NC; ++c) {
    size_t off = base + (size_t)c * 4096;
    float4 v = *(float4*)(S + off);
    *(float4*)(S + off) = hv;
    float la = lam[c];
    hv.x = la * hv.x + v.x;
    hv.y = la * hv.y + v.y;
    hv.z = la * hv.z + v.z;
    hv.w = la * hv.w + v.w;
  }
}

// ---------------------------------------------------------------------------
// Phase 3 (MFMA): per (bh, chunk):
//   Y = diag(e^cls) (C @ h0)  +  (W ⊙ (C @ B^T)) @ X
// Tiles in LDS as bf16, XOR-swizzled. Wave w owns t-rows [16w,16w+16).
// ---------------------------------------------------------------------------
__global__ __launch_bounds__(256, 4) void phase3(
    const float* __restrict__ X, const float* __restrict__ Bm,
    const float* __restrict__ Cm, const float* __restrict__ ws,
    float* __restrict__ Y) {
  const int bid = blockIdx.x;
  const int bh = bid >> 6, c = bid & 63;
  const int b = bh >> 4, h = bh & 15;
  const int tid = threadIdx.x;
  const int l = tid & 63, w = tid >> 6;

  __shared__ unsigned short Cl[64 * 64];  // C  [t][s]  (A-op, row-major)
  __shared__ unsigned short Bl[64 * 64];  // B  [j][s]  (B-op of C B^T)
  __shared__ unsigned short Hl[64 * 64];  // h0^T [d][s] (B-op of C h0); later WG [t][j]
  __shared__ unsigned short Xt[64 * 64];  // X^T [d][j]  (B-op of WG X)
  __shared__ float cl2_s[64], onem_s[64], ecls_s[64];

  const size_t g0 = ((size_t)(b * L + c * T) * NH + h) * 64;
  const int r = tid >> 2, q = tid & 3;
  const size_t grow = g0 + (size_t)r * (NH * 64);
  const float* h0p = ws + S_OFF + (size_t)bid * 4096;

  // ---- stage tiles (f32 -> bf16), swizzled ----
  #pragma unroll
  for (int i = 0; i < 2; ++i) {
    int col = q * 16 + i * 8;
    float4 c0 = *(const float4*)(Cm + grow + col);
    float4 c1 = *(const float4*)(Cm + grow + col + 4);
    float4 b0 = *(const float4*)(Bm + grow + col);
    float4 b1 = *(const float4*)(Bm + grow + col + 4);
    float4 h0 = *(const float4*)(h0p + (size_t)r * 64 + col);
    float4 h1 = *(const float4*)(h0p + (size_t)r * 64 + col + 4);
    float4 x0 = *(const float4*)(X + grow + col);
    float4 x1 = *(const float4*)(X + grow + col + 4);
    int o = swz(r, col);
    short8 cv, bv, hv;
    cv[0]=(short)f2bf(c0.x); cv[1]=(short)f2bf(c0.y); cv[2]=(short)f2bf(c0.z); cv[3]=(short)f2bf(c0.w);
    cv[4]=(short)f2bf(c1.x); cv[5]=(short)f2bf(c1.y); cv[6]=(short)f2bf(c1.z); cv[7]=(short)f2bf(c1.w);
    bv[0]=(short)f2bf(b0.x); bv[1]=(short)f2bf(b0.y); bv[2]=(short)f2bf(b0.z); bv[3]=(short)f2bf(b0.w);
    bv[4]=(short)f2bf(b1.x); bv[5]=(short)f2bf(b1.y); bv[6]=(short)f2bf(b1.z); bv[7]=(short)f2bf(b1.w);
    hv[0]=(short)f2bf(h0.x); hv[1]=(short)f2bf(h0.y); hv[2]=(short)f2bf(h0.z); hv[3]=(short)f2bf(h0.w);
    hv[4]=(short)f2bf(h1.x); hv[5]=(short)f2bf(h1.y); hv[6]=(short)f2bf(h1.z); hv[7]=(short)f2bf(h1.w);
    *(short8*)&Cl[o] = cv;
    *(short8*)&Bl[o] = bv;
    *(short8*)&Hl[o] = hv;
    // X transposed: Xt[d][j] = X[j][d];  row = col+ii (d), column = r (j)
    float xs[8] = {x0.x, x0.y, x0.z, x0.w, x1.x, x1.y, x1.z, x1.w};
    #pragma unroll
    for (int ii = 0; ii < 8; ++ii)
      Xt[swz(col + ii, r)] = f2bf(xs[ii]);
  }
  if (tid < 64) {
    float cls = ws[CLS_OFF + (size_t)bid * T + tid];
    cl2_s[tid]  = cls * 1.44269504088896f;
    ecls_s[tid] = expf(cls);
    onem_s[tid] = ws[ONEM_OFF + (size_t)bid * T + tid];
  }
  __syncthreads();

  const int tr = w * 16;        // wave's t-row base
  const int lr = l & 15;        // lane row within 16-tile
  const int kg = l >> 4;        // k-group 0..3

  // A-frags from C: k in [0,32) and [32,64)
  short8 aC0 = *(const short8*)&Cl[swz(tr + lr,      kg * 8)];
  short8 aC1 = *(const short8*)&Cl[swz(tr + lr, 32 + kg * 8)];

  // ---- matmul1: Z = C @ h0 (B-op from Hl = h0^T [d][s]) ----
  f32x4 acc[4];
  #pragma unroll
  for (int nt = 0; nt < 4; ++nt) { acc[nt][0]=0.f; acc[nt][1]=0.f; acc[nt][2]=0.f; acc[nt][3]=0.f; }
  #pragma unroll
  for (int nt = 0; nt < 4; ++nt) {
    short8 f0 = *(const short8*)&Hl[swz(nt * 16 + lr,      kg * 8)];
    short8 f1 = *(const short8*)&Hl[swz(nt * 16 + lr, 32 + kg * 8)];
    acc[nt] = __builtin_amdgcn_mfma_f32_16x16x32_bf16(aC0, f0, acc[nt], 0, 0, 0);
    acc[nt] = __builtin_amdgcn_mfma_f32_16x16x32_bf16(aC1, f1, acc[nt], 0, 0, 0);
  }
  // scale by e^{cls_t}; row t = tr + kg*4 + reg (C/D layout, m89-verified)
  float e0 = ecls_s[tr + kg * 4 + 0], e1 = ecls_s[tr + kg * 4 + 1];
  float e2 = ecls_s[tr + kg * 4 + 2], e3 = ecls_s[tr + kg * 4 + 3];
  #pragma unroll
  for (int nt = 0; nt < 4; ++nt) {
    acc[nt][0] *= e0; acc[nt][1] *= e1; acc[nt][2] *= e2; acc[nt][3] *= e3;
  }

  // ---- matmul2: G = C @ B^T (B-op from Bl natural [j][s]) ----
  f32x4 g[4];
  #pragma unroll
  for (int nt = 0; nt < 4; ++nt) { g[nt][0]=0.f; g[nt][1]=0.f; g[nt][2]=0.f; g[nt][3]=0.f; }
  #pragma unroll
  for (int nt = 0; nt < 4; ++nt) {
    short8 f0 = *(const short8*)&Bl[swz(nt * 16 + lr,      kg * 8)];
    short8 f1 = *(const short8*)&Bl[swz(nt * 16 + lr, 32 + kg * 8)];
    g[nt] = __builtin_amdgcn_mfma_f32_16x16x32_bf16(aC0, f0, g[nt], 0, 0, 0);
    g[nt] = __builtin_amdgcn_mfma_f32_16x16x32_bf16(aC1, f1, g[nt], 0, 0, 0);
  }
  // mask + weight: W[t][j] = (t>=j) ? exp2(cl2_t - cl2_j) * onem_j : 0
  float c2r[4] = {cl2_s[tr + kg * 4 + 0], cl2_s[tr + kg * 4 + 1],
                  cl2_s[tr + kg * 4 + 2], cl2_s[tr + kg * 4 + 3]};
  #pragma unroll
  for (int nt = 0; nt < 4; ++nt) {
    int j = nt * 16 + lr;
    float c2j = cl2_s[j], om = onem_s[j];
    #pragma unroll
    for (int reg = 0; reg < 4; ++reg) {
      int t = tr + kg * 4 + reg;
      float wgt = (t >= j) ? exp2f(c2r[reg] - c2j) * om : 0.f;
      g[nt][reg] *= wgt;
    }
  }
  __syncthreads();   // all Cl/Bl/Hl fragment reads done

  // write WG (bf16) into Hl's space, row-major [t][j], swizzled
  #pragma unroll
  for (int nt = 0; nt < 4; ++nt)
    #pragma unroll
    for (int reg = 0; reg < 4; ++reg)
      Hl[swz(tr + kg * 4 + reg, nt * 16 + lr)] = f2bf(g[nt][reg]);
  __syncthreads();

  // ---- matmul3: Y += WG @ X (A-op from Hl=WG [t][j], B-op from Xt [d][j]) ----
  short8 aW0 = *(const short8*)&Hl[swz(tr + lr,      kg * 8)];
  short8 aW1 = *(const short8*)&Hl[swz(tr + lr, 32 + kg * 8)];
  #pragma unroll
  for (int nt = 0; nt < 4; ++nt) {
    short8 f0 = *(const short8*)&Xt[swz(nt * 16 + lr,      kg * 8)];
    short8 f1 = *(const short8*)&Xt[swz(nt * 16 + lr, 32 + kg * 8)];
    acc[nt] = __builtin_amdgcn_mfma_f32_16x16x32_bf16(aW0, f0, acc[nt], 0, 0, 0);
    acc[nt] = __builtin_amdgcn_mfma_f32_16x16x32_bf16(aW1, f1, acc[nt], 0, 0, 0);
  }

  // store Y: col d = nt*16 + lr, row t = tr + kg*4 + reg
  #pragma unroll
  for (int reg = 0; reg < 4; ++reg) {
    int t = tr + kg * 4 + reg;
    #pragma unroll
    for (int nt = 0; nt < 4; ++nt) {
      int d = nt * 16 + lr;
      Y[g0 + (size_t)t * (NH * 64) + d] = acc[nt][reg];
    }
  }
}

// ---------------------------------------------------------------------------
// Fallback (round-1) path if ws is too small
// ---------------------------------------------------------------------------
__global__ __launch_bounds__(256) void alpha_kernel(
    const float* __restrict__ X, const float* __restrict__ A,
    const float* __restrict__ Bm,
    const float* __restrict__ l2ab, const float* __restrict__ l2b,
    const float* __restrict__ sema,
    float* __restrict__ alpha_out, int total, int H) {
  int tid = blockIdx.x * 256 + threadIdx.x;
  int item = tid >> 4, sub = tid & 15;
  if (item >= total) return;
  const float4 xv = *(const float4*)(X + (size_t)item * 64 + sub * 4);
  const float4 bv = *(const float4*)(Bm + (size_t)item * 64 + sub * 4);
  float sx = xv.x + xv.y + xv.z + xv.w;
  float sb = bv.x * bv.x + bv.y * bv.y + bv.z * bv.z + bv.w * bv.w;
  #pragma unroll
  for (int m = 1; m < 16; m <<= 1) {
    sx += __shfl_xor(sx, m, 64);
    sb += __shfl_xor(sb, m, 64);
  }
  if (sub == 0) {
    int h = item % H;
    float lab_c = fminf(fmaxf(l2ab[h], -3.32f), -0.015f);
    float beta  = exp2f(fminf(fmaxf(l2b[h], -2.f), 2.f));
    float ema   = sema[h] + 1e-6f;
    alpha_out[item] = alpha_formula(A[item], sx * (1.f/64.f), sb * (1.f/64.f),
                                    lab_c, beta, ema);
  }
}

__global__ __launch_bounds__(256) void scan_kernel(
    const float* __restrict__ X, const float* __restrict__ Bm,
    const float* __restrict__ Cm, const float* __restrict__ alpha_in,
    float* __restrict__ Y, int Ln, int H) {
  int bh = blockIdx.x;
  int b = bh / H, h = bh % H;
  int tid = threadIdx.x;
  int d = tid & 63, w = tid >> 6;
  const size_t rowstride = (size_t)H * 64;
  const size_t base = ((size_t)b * Ln * H + h) * 64;
  const size_t abase = (size_t)b * Ln * H + h;
  __shared__ float xb[2][64], bb2[2][64], cb[2][64], ab_s[2];
  __shared__ float red[2][4][64];
  float hreg[16];
  #pragma unroll
  for (int k = 0; k < 16; ++k) hreg[k] = 0.0f;
  if (w == 0)      xb[0][d]  = X[base + d];
  else if (w == 1) bb2[0][d] = Bm[base + d];
  else if (w == 2) cb[0][d]  = Cm[base + d];
  else if (d == 0) ab_s[0]   = alpha_in[abase];
  __syncthreads();
  for (int t = 0; t < Ln; ++t) {
    const int cur = t & 1, nxt = cur ^ 1;
    float regn = 0.0f;
    if (t + 1 < Ln) {
      size_t off = base + (size_t)(t + 1) * rowstride + d;
      if (w == 0)      regn = X[off];
      else if (w == 1) regn = Bm[off];
      else if (w == 2) regn = Cm[off];
      else if (d == 0) regn = alpha_in[abase + (size_t)(t + 1) * H];
    }
    float al = ab_s[cur];
    float xv = xb[cur][d];
    float t1 = (1.0f - al) * xv;
    float p = 0.0f;
    const float4* bp = (const float4*)&bb2[cur][w * 16];
    const float4* cp = (const float4*)&cb[cur][w * 16];
    #pragma unroll
    for (int k4 = 0; k4 < 4; ++k4) {
      float4 b4 = bp[k4]; float4 c4 = cp[k4];
      hreg[k4*4+0] = al * hreg[k4*4+0] + b4.x * t1;  p += c4.x * hreg[k4*4+0];
      hreg[k4*4+1] = al * hreg[k4*4+1] + b4.y * t1;  p += c4.y * hreg[k4*4+1];
      hreg[k4*4+2] = al * hreg[k4*4+2] + b4.z * t1;  p += c4.z * hreg[k4*4+2];
      hreg[k4*4+3] = al * hreg[k4*4+3] + b4.w * t1;  p += c4.w * hreg[k4*4+3];
    }
    red[cur][w][d] = p;
    if (t + 1 < Ln) {
      if (w == 0)      xb[nxt][d]  = regn;
      else if (w == 1) bb2[nxt][d] = regn;
      else if (w == 2) cb[nxt][d]  = regn;
      else if (d == 0) ab_s[nxt]   = regn;
    }
    __syncthreads();
    if (w == 0) {
      float y = red[cur][0][d] + red[cur][1][d] + red[cur][2][d] + red[cur][3][d];
      Y[base + (size_t)t * rowstride + d] = y;
    }
  }
}

extern "C" void kernel_launch(void* const* d_in, const int* in_sizes, int n_in,
                              void* d_out, int out_size, void* d_ws, size_t ws_size,
                              hipStream_t stream) {
  const float* X    = (const float*)d_in[0];
  const float* A    = (const float*)d_in[1];
  const float* Bm   = (const float*)d_in[2];
  const float* Cm   = (const float*)d_in[3];
  const float* l2ab = (const float*)d_in[4];
  const float* l2b  = (const float*)d_in[5];
  const float* sema = (const float*)d_in[6];
  float* Y = (float*)d_out;
  float* ws = (float*)d_ws;

  if (ws_size >= WS_FLOATS * sizeof(float)) {
    phase1<<<BH * NC, 256, 0, stream>>>(X, A, Bm, l2ab, l2b, sema, ws);
    phase2<<<(BH * 1024) / 256, 256, 0, stream>>>(ws);
    phase3<<<BH * NC, 256, 0, stream>>>(X, Bm, Cm, ws, Y);
  } else {
    const int total = BATCH * L * NH;
    alpha_kernel<<<(total * 16) / 256, 256, 0, stream>>>(X, A, Bm, l2ab, l2b,
                                                         sema, ws, total, NH);
    scan_kernel<<<BH, 256, 0, stream>>>(X, Bm, Cm, ws, Y, L, NH);
  }
}

// Round 4
// 59.959 us; speedup vs baseline: 46.3988x; 1.2624x over previous
//
#include <hip/hip_runtime.h>
#include <hip/hip_bf16.h>
#include <math.h>

constexpr int BATCH = 2, L = 4096, NH = 16;
constexpr int T = 64;              // chunk length
constexpr int NC = L / T;          // 64 chunks
constexpr int BH = BATCH * NH;     // 32 chains

// ws layout (bytes)
constexpr size_t S_OFF    = 0;                                   // f32 [BH][NC][64*64] (S^T: [d][s])
constexpr size_t S_BYTES  = (size_t)BH * NC * 4096 * 4;
constexpr size_t H0_OFF   = S_OFF + S_BYTES;                     // bf16 [BH][NC][64*64] ([d][s])
constexpr size_t H0_BYTES = (size_t)BH * NC * 4096 * 2;
constexpr size_t LAM_OFF  = H0_OFF + H0_BYTES;                   // f32 [BH][NC]
constexpr size_t LAM_BYTES = (size_t)BH * NC * 4;
constexpr size_t CLS_OFF  = LAM_OFF + LAM_BYTES;                 // f32 [BH][NC][T]
constexpr size_t CLS_BYTES = (size_t)BH * NC * T * 4;
constexpr size_t ONEM_OFF = CLS_OFF + CLS_BYTES;                 // f32 [BH][NC][T]
constexpr size_t WS_BYTES = ONEM_OFF + CLS_BYTES;

typedef __attribute__((ext_vector_type(8))) short short8;
typedef __attribute__((ext_vector_type(4))) float f32x4;

__device__ __forceinline__ unsigned short f2bf(float f) {
  union { float f; unsigned u; } v; v.f = f;
  unsigned r = v.u + 0x7FFFu + ((v.u >> 16) & 1u);   // RTNE
  return (unsigned short)(r >> 16);
}
__device__ __forceinline__ float bf2f(unsigned short u) {
  union { unsigned u; float f; } v; v.u = (unsigned)u << 16;
  return v.f;
}

// swizzled u16 index into a [64][64] bf16 LDS tile (16B-granular XOR swizzle)
__device__ __forceinline__ int swz(int row, int col) {
  return row * 64 + (col ^ ((row & 7) << 3));
}

__device__ __forceinline__ float alpha_formula(float Aval, float xbar, float bsq,
                                               float lab_c, float beta, float ema) {
  float ad = expf(Aval);
  float ab = 1.f - exp2f(lab_c);
  float om = 1.f - ad;
  float ns = om * om * xbar * xbar * bsq / ema;
  float boost = fmaxf(tanhf(beta * ns), 0.f);
  return fminf(fmaxf(ab + (1.f - ab) * boost, 0.01f), 0.999f);
}

// ---------------------------------------------------------------------------
// Phase 1 (MFMA): per (bh, chunk): alpha/cls/coeff; S^T[d][s] = sum_j X[j][d] coeff[j] B[j][s]
// ---------------------------------------------------------------------------
__global__ __launch_bounds__(256) void phase1(
    const float* __restrict__ X, const float* __restrict__ A,
    const float* __restrict__ Bm,
    const float* __restrict__ l2ab, const float* __restrict__ l2b,
    const float* __restrict__ sema,
    float* __restrict__ Sp, float* __restrict__ lamp,
    float* __restrict__ clsp, float* __restrict__ onemp) {
  const int bid = blockIdx.x;                 // bh*NC + c
  const int bh = bid >> 6, c = bid & 63;
  const int b = bh >> 4, h = bh & 15;
  const int tid = threadIdx.x;
  const int r = tid >> 2, q = tid & 3;        // row j=r, col-quarter q

  __shared__ unsigned short Xt[64 * 64];      // X^T [d][j]  bf16 swizzled
  __shared__ unsigned short Bt[64 * 64];      // (coeff B)^T [s][j] bf16 swizzled
  __shared__ float xb_s[T], bq_s[T], coeff_s[T];

  const size_t g0 = ((size_t)(b * L + c * T) * NH + h) * 64;
  const size_t grow = g0 + (size_t)r * (NH * 64);

  float xr[16], br[16];
  #pragma unroll
  for (int i = 0; i < 4; ++i) {
    *(float4*)&xr[i * 4] = *(const float4*)(X + grow + q * 16 + i * 4);
    *(float4*)&br[i * 4] = *(const float4*)(Bm + grow + q * 16 + i * 4);
  }
  float sx = 0.f, sb = 0.f;
  #pragma unroll
  for (int i = 0; i < 16; ++i) { sx += xr[i]; sb += br[i] * br[i]; }
  sx += __shfl_xor(sx, 1, 64); sx += __shfl_xor(sx, 2, 64);
  sb += __shfl_xor(sb, 1, 64); sb += __shfl_xor(sb, 2, 64);
  if (q == 0) { xb_s[r] = sx * (1.f / 64.f); bq_s[r] = sb * (1.f / 64.f); }

  // stage X^T (no coeff needed)
  #pragma unroll
  for (int i = 0; i < 16; ++i)
    Xt[swz(q * 16 + i, r)] = f2bf(xr[i]);
  __syncthreads();

  if (tid < 64) {
    float lab_c = fminf(fmaxf(l2ab[h], -3.32f), -0.015f);
    float beta  = exp2f(fminf(fmaxf(l2b[h], -2.f), 2.f));
    float ema   = sema[h] + 1e-6f;
    float Aval  = A[(size_t)(b * L + c * T + tid) * NH + h];
    float al = alpha_formula(Aval, xb_s[tid], bq_s[tid], lab_c, beta, ema);
    float onem = 1.f - al;
    float cls = logf(al);
    #pragma unroll
    for (int off = 1; off < 64; off <<= 1) {
      float o = __shfl_up(cls, off, 64);
      if (tid >= off) cls += o;
    }
    float cls63 = __shfl(cls, 63, 64);
    coeff_s[tid] = expf(cls63 - cls) * onem;
    size_t cb = (size_t)bid * T;
    clsp[cb + tid]  = cls;
    onemp[cb + tid] = onem;
    if (tid == 63) lamp[bid] = expf(cls63);
  }
  __syncthreads();

  // stage (coeff * B)^T
  {
    float cf = coeff_s[r];
    #pragma unroll
    for (int i = 0; i < 16; ++i)
      Bt[swz(q * 16 + i, r)] = f2bf(cf * br[i]);
  }
  __syncthreads();

  // MFMA: S^T[d][s]; wave w owns d-rows [16w, 16w+16)
  const int l = tid & 63, w = tid >> 6;
  const int tr = w * 16, lr = l & 15, kg = l >> 4;
  short8 aX0 = *(const short8*)&Xt[swz(tr + lr,      kg * 8)];
  short8 aX1 = *(const short8*)&Xt[swz(tr + lr, 32 + kg * 8)];
  f32x4 acc[4];
  #pragma unroll
  for (int nt = 0; nt < 4; ++nt) { acc[nt][0]=0.f; acc[nt][1]=0.f; acc[nt][2]=0.f; acc[nt][3]=0.f; }
  #pragma unroll
  for (int nt = 0; nt < 4; ++nt) {
    short8 f0 = *(const short8*)&Bt[swz(nt * 16 + lr,      kg * 8)];
    short8 f1 = *(const short8*)&Bt[swz(nt * 16 + lr, 32 + kg * 8)];
    acc[nt] = __builtin_amdgcn_mfma_f32_16x16x32_bf16(aX0, f0, acc[nt], 0, 0, 0);
    acc[nt] = __builtin_amdgcn_mfma_f32_16x16x32_bf16(aX1, f1, acc[nt], 0, 0, 0);
  }
  float* Sb = Sp + (size_t)bid * 4096;
  #pragma unroll
  for (int reg = 0; reg < 4; ++reg) {
    int d = tr + kg * 4 + reg;
    #pragma unroll
    for (int nt = 0; nt < 4; ++nt)
      Sb[(size_t)d * 64 + nt * 16 + lr] = acc[nt][reg];
  }
}

// ---------------------------------------------------------------------------
// Phase 2: exclusive chunk-scan; reads S (f32), writes h0 (bf16).
// Recurrence stays in f32 registers; bf16 rounding is output-only.
// ---------------------------------------------------------------------------
__global__ __launch_bounds__(256) void phase2(
    const float* __restrict__ Sp, const float* __restrict__ lamp,
    unsigned int* __restrict__ H0 /* as u32 pairs */) {
  const int gtid = blockIdx.x * 256 + threadIdx.x;   // BH*2048 threads
  const int bh = gtid >> 11;
  const int e2 = (gtid & 2047) * 2;                  // element pair index
  const float* lam = lamp + (size_t)bh * NC;
  const size_t base = (size_t)bh * NC * 4096 + e2;
  float h0v = 0.f, h1v = 0.f;
  #pragma unroll 4
  for (int c = 0; c < NC; ++c) {
    size_t off = base + (size_t)c * 4096;
    float2 v = *(const float2*)(Sp + off);
    H0[off >> 1] = (unsigned)f2bf(h0v) | ((unsigned)f2bf(h1v) << 16);
    float la = lam[c];
    h0v = la * h0v + v.x;
    h1v = la * h1v + v.y;
  }
}

// ---------------------------------------------------------------------------
// Phase 3 (MFMA): Y = diag(e^cls) (C @ h0) + (W ⊙ (C @ B^T)) @ X
// ---------------------------------------------------------------------------
__global__ __launch_bounds__(256) void phase3(
    const float* __restrict__ X, const float* __restrict__ Bm,
    const float* __restrict__ Cm, const unsigned short* __restrict__ H0,
    const float* __restrict__ clsp, const float* __restrict__ onemp,
    float* __restrict__ Y) {
  const int bid = blockIdx.x;
  const int bh = bid >> 6, c = bid & 63;
  const int b = bh >> 4, h = bh & 15;
  const int tid = threadIdx.x;
  const int l = tid & 63, w = tid >> 6;

  __shared__ unsigned short Cl[64 * 64];  // C  [t][s]  (A-op)
  __shared__ unsigned short Bl[64 * 64];  // B  [j][s]  (B-op of C B^T)
  __shared__ unsigned short Hl[64 * 64];  // h0^T [d][s]; later WG [t][j]
  __shared__ unsigned short Xt[64 * 64];  // X^T [d][j]
  __shared__ float cl2_s[64], onem_s[64], ecls_s[64];

  const size_t g0 = ((size_t)(b * L + c * T) * NH + h) * 64;
  const int r = tid >> 2, q = tid & 3;
  const size_t grow = g0 + (size_t)r * (NH * 64);
  const unsigned short* h0p = H0 + (size_t)bid * 4096;

  #pragma unroll
  for (int i = 0; i < 2; ++i) {
    int col = q * 16 + i * 8;
    float4 c0 = *(const float4*)(Cm + grow + col);
    float4 c1 = *(const float4*)(Cm + grow + col + 4);
    float4 b0 = *(const float4*)(Bm + grow + col);
    float4 b1 = *(const float4*)(Bm + grow + col + 4);
    float4 x0 = *(const float4*)(X + grow + col);
    float4 x1 = *(const float4*)(X + grow + col + 4);
    short8 hv = *(const short8*)(h0p + (size_t)r * 64 + col);   // bf16 direct
    int o = swz(r, col);
    short8 cv, bv;
    cv[0]=(short)f2bf(c0.x); cv[1]=(short)f2bf(c0.y); cv[2]=(short)f2bf(c0.z); cv[3]=(short)f2bf(c0.w);
    cv[4]=(short)f2bf(c1.x); cv[5]=(short)f2bf(c1.y); cv[6]=(short)f2bf(c1.z); cv[7]=(short)f2bf(c1.w);
    bv[0]=(short)f2bf(b0.x); bv[1]=(short)f2bf(b0.y); bv[2]=(short)f2bf(b0.z); bv[3]=(short)f2bf(b0.w);
    bv[4]=(short)f2bf(b1.x); bv[5]=(short)f2bf(b1.y); bv[6]=(short)f2bf(b1.z); bv[7]=(short)f2bf(b1.w);
    *(short8*)&Cl[o] = cv;
    *(short8*)&Bl[o] = bv;
    *(short8*)&Hl[o] = hv;
    float xs[8] = {x0.x, x0.y, x0.z, x0.w, x1.x, x1.y, x1.z, x1.w};
    #pragma unroll
    for (int ii = 0; ii < 8; ++ii)
      Xt[swz(col + ii, r)] = f2bf(xs[ii]);
  }
  if (tid < 64) {
    float cls = clsp[(size_t)bid * T + tid];
    cl2_s[tid]  = cls * 1.44269504088896f;
    ecls_s[tid] = expf(cls);
    onem_s[tid] = onemp[(size_t)bid * T + tid];
  }
  __syncthreads();

  const int tr = w * 16, lr = l & 15, kg = l >> 4;

  short8 aC0 = *(const short8*)&Cl[swz(tr + lr,      kg * 8)];
  short8 aC1 = *(const short8*)&Cl[swz(tr + lr, 32 + kg * 8)];

  // matmul1: Z = C @ h0
  f32x4 acc[4];
  #pragma unroll
  for (int nt = 0; nt < 4; ++nt) { acc[nt][0]=0.f; acc[nt][1]=0.f; acc[nt][2]=0.f; acc[nt][3]=0.f; }
  #pragma unroll
  for (int nt = 0; nt < 4; ++nt) {
    short8 f0 = *(const short8*)&Hl[swz(nt * 16 + lr,      kg * 8)];
    short8 f1 = *(const short8*)&Hl[swz(nt * 16 + lr, 32 + kg * 8)];
    acc[nt] = __builtin_amdgcn_mfma_f32_16x16x32_bf16(aC0, f0, acc[nt], 0, 0, 0);
    acc[nt] = __builtin_amdgcn_mfma_f32_16x16x32_bf16(aC1, f1, acc[nt], 0, 0, 0);
  }
  float e0 = ecls_s[tr + kg * 4 + 0], e1 = ecls_s[tr + kg * 4 + 1];
  float e2 = ecls_s[tr + kg * 4 + 2], e3 = ecls_s[tr + kg * 4 + 3];
  #pragma unroll
  for (int nt = 0; nt < 4; ++nt) {
    acc[nt][0] *= e0; acc[nt][1] *= e1; acc[nt][2] *= e2; acc[nt][3] *= e3;
  }

  // matmul2: G = C @ B^T
  f32x4 g[4];
  #pragma unroll
  for (int nt = 0; nt < 4; ++nt) { g[nt][0]=0.f; g[nt][1]=0.f; g[nt][2]=0.f; g[nt][3]=0.f; }
  #pragma unroll
  for (int nt = 0; nt < 4; ++nt) {
    short8 f0 = *(const short8*)&Bl[swz(nt * 16 + lr,      kg * 8)];
    short8 f1 = *(const short8*)&Bl[swz(nt * 16 + lr, 32 + kg * 8)];
    g[nt] = __builtin_amdgcn_mfma_f32_16x16x32_bf16(aC0, f0, g[nt], 0, 0, 0);
    g[nt] = __builtin_amdgcn_mfma_f32_16x16x32_bf16(aC1, f1, g[nt], 0, 0, 0);
  }
  float c2r[4] = {cl2_s[tr + kg * 4 + 0], cl2_s[tr + kg * 4 + 1],
                  cl2_s[tr + kg * 4 + 2], cl2_s[tr + kg * 4 + 3]};
  #pragma unroll
  for (int nt = 0; nt < 4; ++nt) {
    int j = nt * 16 + lr;
    float c2j = cl2_s[j], om = onem_s[j];
    #pragma unroll
    for (int reg = 0; reg < 4; ++reg) {
      int t = tr + kg * 4 + reg;
      float wgt = (t >= j) ? exp2f(c2r[reg] - c2j) * om : 0.f;
      g[nt][reg] *= wgt;
    }
  }
  __syncthreads();

  #pragma unroll
  for (int nt = 0; nt < 4; ++nt)
    #pragma unroll
    for (int reg = 0; reg < 4; ++reg)
      Hl[swz(tr + kg * 4 + reg, nt * 16 + lr)] = f2bf(g[nt][reg]);
  __syncthreads();

  // matmul3: Y += WG @ X
  short8 aW0 = *(const short8*)&Hl[swz(tr + lr,      kg * 8)];
  short8 aW1 = *(const short8*)&Hl[swz(tr + lr, 32 + kg * 8)];
  #pragma unroll
  for (int nt = 0; nt < 4; ++nt) {
    short8 f0 = *(const short8*)&Xt[swz(nt * 16 + lr,      kg * 8)];
    short8 f1 = *(const short8*)&Xt[swz(nt * 16 + lr, 32 + kg * 8)];
    acc[nt] = __builtin_amdgcn_mfma_f32_16x16x32_bf16(aW0, f0, acc[nt], 0, 0, 0);
    acc[nt] = __builtin_amdgcn_mfma_f32_16x16x32_bf16(aW1, f1, acc[nt], 0, 0, 0);
  }

  #pragma unroll
  for (int reg = 0; reg < 4; ++reg) {
    int t = tr + kg * 4 + reg;
    #pragma unroll
    for (int nt = 0; nt < 4; ++nt)
      Y[g0 + (size_t)t * (NH * 64) + nt * 16 + lr] = acc[nt][reg];
  }
}

// ---------------------------------------------------------------------------
// Fallback (round-1) path if ws is too small
// ---------------------------------------------------------------------------
__global__ __launch_bounds__(256) void alpha_kernel(
    const float* __restrict__ X, const float* __restrict__ A,
    const float* __restrict__ Bm,
    const float* __restrict__ l2ab, const float* __restrict__ l2b,
    const float* __restrict__ sema,
    float* __restrict__ alpha_out, int total, int H) {
  int tid = blockIdx.x * 256 + threadIdx.x;
  int item = tid >> 4, sub = tid & 15;
  if (item >= total) return;
  const float4 xv = *(const float4*)(X + (size_t)item * 64 + sub * 4);
  const float4 bv = *(const float4*)(Bm + (size_t)item * 64 + sub * 4);
  float sx = xv.x + xv.y + xv.z + xv.w;
  float sb = bv.x * bv.x + bv.y * bv.y + bv.z * bv.z + bv.w * bv.w;
  #pragma unroll
  for (int m = 1; m < 16; m <<= 1) {
    sx += __shfl_xor(sx, m, 64);
    sb += __shfl_xor(sb, m, 64);
  }
  if (sub == 0) {
    int h = item % H;
    float lab_c = fminf(fmaxf(l2ab[h], -3.32f), -0.015f);
    float beta  = exp2f(fminf(fmaxf(l2b[h], -2.f), 2.f));
    float ema   = sema[h] + 1e-6f;
    alpha_out[item] = alpha_formula(A[item], sx * (1.f/64.f), sb * (1.f/64.f),
                                    lab_c, beta, ema);
  }
}

__global__ __launch_bounds__(256) void scan_kernel(
    const float* __restrict__ X, const float* __restrict__ Bm,
    const float* __restrict__ Cm, const float* __restrict__ alpha_in,
    float* __restrict__ Y, int Ln, int H) {
  int bh = blockIdx.x;
  int b = bh / H, h = bh % H;
  int tid = threadIdx.x;
  int d = tid & 63, w = tid >> 6;
  const size_t rowstride = (size_t)H * 64;
  const size_t base = ((size_t)b * Ln * H + h) * 64;
  const size_t abase = (size_t)b * Ln * H + h;
  __shared__ float xb[2][64], bb2[2][64], cb[2][64], ab_s[2];
  __shared__ float red[2][4][64];
  float hreg[16];
  #pragma unroll
  for (int k = 0; k < 16; ++k) hreg[k] = 0.0f;
  if (w == 0)      xb[0][d]  = X[base + d];
  else if (w == 1) bb2[0][d] = Bm[base + d];
  else if (w == 2) cb[0][d]  = Cm[base + d];
  else if (d == 0) ab_s[0]   = alpha_in[abase];
  __syncthreads();
  for (int t = 0; t < Ln; ++t) {
    const int cur = t & 1, nxt = cur ^ 1;
    float regn = 0.0f;
    if (t + 1 < Ln) {
      size_t off = base + (size_t)(t + 1) * rowstride + d;
      if (w == 0)      regn = X[off];
      else if (w == 1) regn = Bm[off];
      else if (w == 2) regn = Cm[off];
      else if (d == 0) regn = alpha_in[abase + (size_t)(t + 1) * H];
    }
    float al = ab_s[cur];
    float xv = xb[cur][d];
    float t1 = (1.0f - al) * xv;
    float p = 0.0f;
    const float4* bp = (const float4*)&bb2[cur][w * 16];
    const float4* cp = (const float4*)&cb[cur][w * 16];
    #pragma unroll
    for (int k4 = 0; k4 < 4; ++k4) {
      float4 b4 = bp[k4]; float4 c4 = cp[k4];
      hreg[k4*4+0] = al * hreg[k4*4+0] + b4.x * t1;  p += c4.x * hreg[k4*4+0];
      hreg[k4*4+1] = al * hreg[k4*4+1] + b4.y * t1;  p += c4.y * hreg[k4*4+1];
      hreg[k4*4+2] = al * hreg[k4*4+2] + b4.z * t1;  p += c4.z * hreg[k4*4+2];
      hreg[k4*4+3] = al * hreg[k4*4+3] + b4.w * t1;  p += c4.w * hreg[k4*4+3];
    }
    red[cur][w][d] = p;
    if (t + 1 < Ln) {
      if (w == 0)      xb[nxt][d]  = regn;
      else if (w == 1) bb2[nxt][d] = regn;
      else if (w == 2) cb[nxt][d]  = regn;
      else if (d == 0) ab_s[nxt]   = regn;
    }
    __syncthreads();
    if (w == 0) {
      float y = red[cur][0][d] + red[cur][1][d] + red[cur][2][d] + red[cur][3][d];
      Y[base + (size_t)t * rowstride + d] = y;
    }
  }
}

extern "C" void kernel_launch(void* const* d_in, const int* in_sizes, int n_in,
                              void* d_out, int out_size, void* d_ws, size_t ws_size,
                              hipStream_t stream) {
  const float* X    = (const float*)d_in[0];
  const float* A    = (const float*)d_in[1];
  const float* Bm   = (const float*)d_in[2];
  const float* Cm   = (const float*)d_in[3];
  const float* l2ab = (const float*)d_in[4];
  const float* l2b  = (const float*)d_in[5];
  const float* sema = (const float*)d_in[6];
  float* Y = (float*)d_out;
  char* wsb = (char*)d_ws;

  if (ws_size >= WS_BYTES) {
    float* Sp            = (float*)(wsb + S_OFF);
    unsigned short* H0   = (unsigned short*)(wsb + H0_OFF);
    float* lamp          = (float*)(wsb + LAM_OFF);
    float* clsp          = (float*)(wsb + CLS_OFF);
    float* onemp         = (float*)(wsb + ONEM_OFF);
    phase1<<<BH * NC, 256, 0, stream>>>(X, A, Bm, l2ab, l2b, sema,
                                        Sp, lamp, clsp, onemp);
    phase2<<<(BH * 2048) / 256, 256, 0, stream>>>(Sp, lamp, (unsigned int*)H0);
    phase3<<<BH * NC, 256, 0, stream>>>(X, Bm, Cm, H0, clsp, onemp, Y);
  } else {
    const int total = BATCH * L * NH;
    alpha_kernel<<<(total * 16) / 256, 256, 0, stream>>>(X, A, Bm, l2ab, l2b,
                                                         sema, (float*)wsb, total, NH);
    scan_kernel<<<BH, 256, 0, stream>>>(X, Bm, Cm, (float*)wsb, Y, L, NH);
  }
}

// Round 5
// 58.006 us; speedup vs baseline: 47.9607x; 1.0337x over previous
//
#include <hip/hip_runtime.h>
#include <hip/hip_bf16.h>
#include <math.h>

constexpr int BATCH = 2, L = 4096, NH = 16;
constexpr int T = 64;              // chunk length
constexpr int NC = L / T;          // 64 chunks
constexpr int BH = BATCH * NH;     // 32 chains

// ws layout (bytes)
constexpr size_t S_OFF    = 0;                                   // bf16 [BH][NC][64*64] (S^T: [d][s])
constexpr size_t S_BYTES  = (size_t)BH * NC * 4096 * 2;
constexpr size_t H0_OFF   = S_OFF + S_BYTES;                     // bf16 [BH][NC][64*64] ([d][s])
constexpr size_t H0_BYTES = (size_t)BH * NC * 4096 * 2;
constexpr size_t LAM_OFF  = H0_OFF + H0_BYTES;                   // f32 [BH][NC]
constexpr size_t LAM_BYTES = (size_t)BH * NC * 4;
constexpr size_t CLS_OFF  = LAM_OFF + LAM_BYTES;                 // f32 [BH][NC][T]
constexpr size_t CLS_BYTES = (size_t)BH * NC * T * 4;
constexpr size_t ONEM_OFF = CLS_OFF + CLS_BYTES;                 // f32 [BH][NC][T]
constexpr size_t WS_BYTES = ONEM_OFF + CLS_BYTES;

typedef __attribute__((ext_vector_type(8))) short short8;
typedef __attribute__((ext_vector_type(4))) float f32x4;

__device__ __forceinline__ unsigned short f2bf(float f) {
  union { float f; unsigned u; } v; v.f = f;
  unsigned r = v.u + 0x7FFFu + ((v.u >> 16) & 1u);   // RTNE
  return (unsigned short)(r >> 16);
}
__device__ __forceinline__ float bf2f(unsigned short u) {
  union { unsigned u; float f; } v; v.u = (unsigned)u << 16;
  return v.f;
}

// swizzled u16 index into a [64][64] bf16 LDS tile (16B-granular XOR swizzle)
__device__ __forceinline__ int swz(int row, int col) {
  return row * 64 + (col ^ ((row & 7) << 3));
}

__device__ __forceinline__ float alpha_formula(float Aval, float xbar, float bsq,
                                               float lab_c, float beta, float ema) {
  float ad = expf(Aval);
  float ab = 1.f - exp2f(lab_c);
  float om = 1.f - ad;
  float ns = om * om * xbar * xbar * bsq / ema;
  float boost = fmaxf(tanhf(beta * ns), 0.f);
  return fminf(fmaxf(ab + (1.f - ab) * boost, 0.01f), 0.999f);
}

// ---------------------------------------------------------------------------
// Phase 1 (MFMA): per (bh, chunk): alpha/cls/coeff;
//   S^T[d][s] = sum_j X[j][d] coeff[j] B[j][s]   (stored bf16, LDS-repacked)
// ---------------------------------------------------------------------------
__global__ __launch_bounds__(256) void phase1(
    const float* __restrict__ X, const float* __restrict__ A,
    const float* __restrict__ Bm,
    const float* __restrict__ l2ab, const float* __restrict__ l2b,
    const float* __restrict__ sema,
    unsigned short* __restrict__ Sp, float* __restrict__ lamp,
    float* __restrict__ clsp, float* __restrict__ onemp) {
  const int bid = blockIdx.x;                 // bh*NC + c
  const int bh = bid >> 6, c = bid & 63;
  const int b = bh >> 4, h = bh & 15;
  const int tid = threadIdx.x;
  const int r = tid >> 2, q = tid & 3;        // row j=r, col-quarter q

  __shared__ unsigned short Xt[64 * 64];      // X^T [d][j]  bf16 swizzled; later S repack
  __shared__ unsigned short Bt[64 * 64];      // (coeff B)^T [s][j] bf16 swizzled
  __shared__ float xb_s[T], bq_s[T], coeff_s[T];

  const size_t g0 = ((size_t)(b * L + c * T) * NH + h) * 64;
  const size_t grow = g0 + (size_t)r * (NH * 64);

  float xr[16], br[16];
  #pragma unroll
  for (int i = 0; i < 4; ++i) {
    *(float4*)&xr[i * 4] = *(const float4*)(X + grow + q * 16 + i * 4);
    *(float4*)&br[i * 4] = *(const float4*)(Bm + grow + q * 16 + i * 4);
  }
  float sx = 0.f, sb = 0.f;
  #pragma unroll
  for (int i = 0; i < 16; ++i) { sx += xr[i]; sb += br[i] * br[i]; }
  sx += __shfl_xor(sx, 1, 64); sx += __shfl_xor(sx, 2, 64);
  sb += __shfl_xor(sb, 1, 64); sb += __shfl_xor(sb, 2, 64);
  if (q == 0) { xb_s[r] = sx * (1.f / 64.f); bq_s[r] = sb * (1.f / 64.f); }

  // stage X^T
  #pragma unroll
  for (int i = 0; i < 16; ++i)
    Xt[swz(q * 16 + i, r)] = f2bf(xr[i]);
  __syncthreads();

  if (tid < 64) {
    float lab_c = fminf(fmaxf(l2ab[h], -3.32f), -0.015f);
    float beta  = exp2f(fminf(fmaxf(l2b[h], -2.f), 2.f));
    float ema   = sema[h] + 1e-6f;
    float Aval  = A[(size_t)(b * L + c * T + tid) * NH + h];
    float al = alpha_formula(Aval, xb_s[tid], bq_s[tid], lab_c, beta, ema);
    float onem = 1.f - al;
    float cls = logf(al);
    #pragma unroll
    for (int off = 1; off < 64; off <<= 1) {
      float o = __shfl_up(cls, off, 64);
      if (tid >= off) cls += o;
    }
    float cls63 = __shfl(cls, 63, 64);
    coeff_s[tid] = expf(cls63 - cls) * onem;
    size_t cb = (size_t)bid * T;
    clsp[cb + tid]  = cls;
    onemp[cb + tid] = onem;
    if (tid == 63) lamp[bid] = expf(cls63);
  }
  __syncthreads();

  // stage (coeff * B)^T
  {
    float cf = coeff_s[r];
    #pragma unroll
    for (int i = 0; i < 16; ++i)
      Bt[swz(q * 16 + i, r)] = f2bf(cf * br[i]);
  }
  __syncthreads();

  // MFMA: S^T[d][s]; wave w owns d-rows [16w, 16w+16)
  const int l = tid & 63, w = tid >> 6;
  const int tr = w * 16, lr = l & 15, kg = l >> 4;
  short8 aX0 = *(const short8*)&Xt[swz(tr + lr,      kg * 8)];
  short8 aX1 = *(const short8*)&Xt[swz(tr + lr, 32 + kg * 8)];
  f32x4 acc[4];
  #pragma unroll
  for (int nt = 0; nt < 4; ++nt) { acc[nt][0]=0.f; acc[nt][1]=0.f; acc[nt][2]=0.f; acc[nt][3]=0.f; }
  #pragma unroll
  for (int nt = 0; nt < 4; ++nt) {
    short8 f0 = *(const short8*)&Bt[swz(nt * 16 + lr,      kg * 8)];
    short8 f1 = *(const short8*)&Bt[swz(nt * 16 + lr, 32 + kg * 8)];
    acc[nt] = __builtin_amdgcn_mfma_f32_16x16x32_bf16(aX0, f0, acc[nt], 0, 0, 0);
    acc[nt] = __builtin_amdgcn_mfma_f32_16x16x32_bf16(aX1, f1, acc[nt], 0, 0, 0);
  }

  __syncthreads();   // all Xt/Bt fragment reads complete; Xt reusable
  // repack S (bf16) into LDS, swizzled; rows d, cols s
  #pragma unroll
  for (int nt = 0; nt < 4; ++nt)
    #pragma unroll
    for (int reg = 0; reg < 4; ++reg)
      Xt[swz(tr + kg * 4 + reg, nt * 16 + lr)] = f2bf(acc[nt][reg]);
  __syncthreads();

  // coalesced copy-out: 512 short8 groups; thread handles groups tid and 256+tid
  unsigned short* Sb = Sp + (size_t)bid * 4096;
  #pragma unroll
  for (int g2 = 0; g2 < 2; ++g2) {
    int g = g2 * 256 + tid;        // 0..511
    int row = g >> 3, c8 = (g & 7) * 8;
    short8 v = *(const short8*)&Xt[swz(row, c8)];
    *(short8*)(Sb + row * 64 + c8) = v;
  }
}

// ---------------------------------------------------------------------------
// Phase 2: exclusive chunk-scan; reads S (bf16), writes h0 (bf16).
// Recurrence stays in f32 registers; rounding is I/O-only.
// ---------------------------------------------------------------------------
__global__ __launch_bounds__(256) void phase2(
    const unsigned int* __restrict__ Sp, const float* __restrict__ lamp,
    unsigned int* __restrict__ H0) {
  const int gtid = blockIdx.x * 256 + threadIdx.x;   // BH*2048 threads
  const int bh = gtid >> 11;
  const int e2 = gtid & 2047;                        // u32 (pair) index in chunk
  const float* lam = lamp + (size_t)bh * NC;
  const size_t base = (size_t)bh * NC * 2048 + e2;   // u32 units
  float h0v = 0.f, h1v = 0.f;
  #pragma unroll 4
  for (int c = 0; c < NC; ++c) {
    size_t off = base + (size_t)c * 2048;
    unsigned v = Sp[off];
    H0[off] = (unsigned)f2bf(h0v) | ((unsigned)f2bf(h1v) << 16);
    float la = lam[c];
    h0v = la * h0v + bf2f((unsigned short)(v & 0xFFFFu));
    h1v = la * h1v + bf2f((unsigned short)(v >> 16));
  }
}

// ---------------------------------------------------------------------------
// Phase 3 (MFMA): Y = diag(e^cls) (C @ h0) + (W ⊙ (C @ B^T)) @ X
// ---------------------------------------------------------------------------
__global__ __launch_bounds__(256) void phase3(
    const float* __restrict__ X, const float* __restrict__ Bm,
    const float* __restrict__ Cm, const unsigned short* __restrict__ H0,
    const float* __restrict__ clsp, const float* __restrict__ onemp,
    float* __restrict__ Y) {
  const int bid = blockIdx.x;
  const int bh = bid >> 6, c = bid & 63;
  const int b = bh >> 4, h = bh & 15;
  const int tid = threadIdx.x;
  const int l = tid & 63, w = tid >> 6;

  __shared__ unsigned short Cl[64 * 64];  // C  [t][s]  (A-op)
  __shared__ unsigned short Bl[64 * 64];  // B  [j][s]  (B-op of C B^T)
  __shared__ unsigned short Hl[64 * 64];  // h0^T [d][s]; later WG [t][j]
  __shared__ unsigned short Xt[64 * 64];  // X^T [d][j]
  __shared__ float cl2_s[64], onem_s[64], ecls_s[64];

  const size_t g0 = ((size_t)(b * L + c * T) * NH + h) * 64;
  const int r = tid >> 2, q = tid & 3;
  const size_t grow = g0 + (size_t)r * (NH * 64);
  const unsigned short* h0p = H0 + (size_t)bid * 4096;

  #pragma unroll
  for (int i = 0; i < 2; ++i) {
    int col = q * 16 + i * 8;
    float4 c0 = *(const float4*)(Cm + grow + col);
    float4 c1 = *(const float4*)(Cm + grow + col + 4);
    float4 b0 = *(const float4*)(Bm + grow + col);
    float4 b1 = *(const float4*)(Bm + grow + col + 4);
    float4 x0 = *(const float4*)(X + grow + col);
    float4 x1 = *(const float4*)(X + grow + col + 4);
    short8 hv = *(const short8*)(h0p + (size_t)r * 64 + col);   // bf16 direct
    int o = swz(r, col);
    short8 cv, bv;
    cv[0]=(short)f2bf(c0.x); cv[1]=(short)f2bf(c0.y); cv[2]=(short)f2bf(c0.z); cv[3]=(short)f2bf(c0.w);
    cv[4]=(short)f2bf(c1.x); cv[5]=(short)f2bf(c1.y); cv[6]=(short)f2bf(c1.z); cv[7]=(short)f2bf(c1.w);
    bv[0]=(short)f2bf(b0.x); bv[1]=(short)f2bf(b0.y); bv[2]=(short)f2bf(b0.z); bv[3]=(short)f2bf(b0.w);
    bv[4]=(short)f2bf(b1.x); bv[5]=(short)f2bf(b1.y); bv[6]=(short)f2bf(b1.z); bv[7]=(short)f2bf(b1.w);
    *(short8*)&Cl[o] = cv;
    *(short8*)&Bl[o] = bv;
    *(short8*)&Hl[o] = hv;
    float xs[8] = {x0.x, x0.y, x0.z, x0.w, x1.x, x1.y, x1.z, x1.w};
    #pragma unroll
    for (int ii = 0; ii < 8; ++ii)
      Xt[swz(col + ii, r)] = f2bf(xs[ii]);
  }
  if (tid < 64) {
    float cls = clsp[(size_t)bid * T + tid];
    cl2_s[tid]  = cls * 1.44269504088896f;
    ecls_s[tid] = expf(cls);
    onem_s[tid] = onemp[(size_t)bid * T + tid];
  }
  __syncthreads();

  const int tr = w * 16, lr = l & 15, kg = l >> 4;

  short8 aC0 = *(const short8*)&Cl[swz(tr + lr,      kg * 8)];
  short8 aC1 = *(const short8*)&Cl[swz(tr + lr, 32 + kg * 8)];

  // matmul1: Z = C @ h0
  f32x4 acc[4];
  #pragma unroll
  for (int nt = 0; nt < 4; ++nt) { acc[nt][0]=0.f; acc[nt][1]=0.f; acc[nt][2]=0.f; acc[nt][3]=0.f; }
  #pragma unroll
  for (int nt = 0; nt < 4; ++nt) {
    short8 f0 = *(const short8*)&Hl[swz(nt * 16 + lr,      kg * 8)];
    short8 f1 = *(const short8*)&Hl[swz(nt * 16 + lr, 32 + kg * 8)];
    acc[nt] = __builtin_amdgcn_mfma_f32_16x16x32_bf16(aC0, f0, acc[nt], 0, 0, 0);
    acc[nt] = __builtin_amdgcn_mfma_f32_16x16x32_bf16(aC1, f1, acc[nt], 0, 0, 0);
  }
  float e0 = ecls_s[tr + kg * 4 + 0], e1 = ecls_s[tr + kg * 4 + 1];
  float e2 = ecls_s[tr + kg * 4 + 2], e3 = ecls_s[tr + kg * 4 + 3];
  #pragma unroll
  for (int nt = 0; nt < 4; ++nt) {
    acc[nt][0] *= e0; acc[nt][1] *= e1; acc[nt][2] *= e2; acc[nt][3] *= e3;
  }

  // matmul2: G = C @ B^T
  f32x4 g[4];
  #pragma unroll
  for (int nt = 0; nt < 4; ++nt) { g[nt][0]=0.f; g[nt][1]=0.f; g[nt][2]=0.f; g[nt][3]=0.f; }
  #pragma unroll
  for (int nt = 0; nt < 4; ++nt) {
    short8 f0 = *(const short8*)&Bl[swz(nt * 16 + lr,      kg * 8)];
    short8 f1 = *(const short8*)&Bl[swz(nt * 16 + lr, 32 + kg * 8)];
    g[nt] = __builtin_amdgcn_mfma_f32_16x16x32_bf16(aC0, f0, g[nt], 0, 0, 0);
    g[nt] = __builtin_amdgcn_mfma_f32_16x16x32_bf16(aC1, f1, g[nt], 0, 0, 0);
  }
  float c2r[4] = {cl2_s[tr + kg * 4 + 0], cl2_s[tr + kg * 4 + 1],
                  cl2_s[tr + kg * 4 + 2], cl2_s[tr + kg * 4 + 3]};
  #pragma unroll
  for (int nt = 0; nt < 4; ++nt) {
    int j = nt * 16 + lr;
    float c2j = cl2_s[j], om = onem_s[j];
    #pragma unroll
    for (int reg = 0; reg < 4; ++reg) {
      int t = tr + kg * 4 + reg;
      float wgt = (t >= j) ? exp2f(c2r[reg] - c2j) * om : 0.f;
      g[nt][reg] *= wgt;
    }
  }
  __syncthreads();

  #pragma unroll
  for (int nt = 0; nt < 4; ++nt)
    #pragma unroll
    for (int reg = 0; reg < 4; ++reg)
      Hl[swz(tr + kg * 4 + reg, nt * 16 + lr)] = f2bf(g[nt][reg]);
  __syncthreads();

  // matmul3: Y += WG @ X
  short8 aW0 = *(const short8*)&Hl[swz(tr + lr,      kg * 8)];
  short8 aW1 = *(const short8*)&Hl[swz(tr + lr, 32 + kg * 8)];
  #pragma unroll
  for (int nt = 0; nt < 4; ++nt) {
    short8 f0 = *(const short8*)&Xt[swz(nt * 16 + lr,      kg * 8)];
    short8 f1 = *(const short8*)&Xt[swz(nt * 16 + lr, 32 + kg * 8)];
    acc[nt] = __builtin_amdgcn_mfma_f32_16x16x32_bf16(aW0, f0, acc[nt], 0, 0, 0);
    acc[nt] = __builtin_amdgcn_mfma_f32_16x16x32_bf16(aW1, f1, acc[nt], 0, 0, 0);
  }

  #pragma unroll
  for (int reg = 0; reg < 4; ++reg) {
    int t = tr + kg * 4 + reg;
    #pragma unroll
    for (int nt = 0; nt < 4; ++nt)
      Y[g0 + (size_t)t * (NH * 64) + nt * 16 + lr] = acc[nt][reg];
  }
}

// ---------------------------------------------------------------------------
// Fallback (round-1) path if ws is too small
// ---------------------------------------------------------------------------
__global__ __launch_bounds__(256) void alpha_kernel(
    const float* __restrict__ X, const float* __restrict__ A,
    const float* __restrict__ Bm,
    const float* __restrict__ l2ab, const float* __restrict__ l2b,
    const float* __restrict__ sema,
    float* __restrict__ alpha_out, int total, int H) {
  int tid = blockIdx.x * 256 + threadIdx.x;
  int item = tid >> 4, sub = tid & 15;
  if (item >= total) return;
  const float4 xv = *(const float4*)(X + (size_t)item * 64 + sub * 4);
  const float4 bv = *(const float4*)(Bm + (size_t)item * 64 + sub * 4);
  float sx = xv.x + xv.y + xv.z + xv.w;
  float sb = bv.x * bv.x + bv.y * bv.y + bv.z * bv.z + bv.w * bv.w;
  #pragma unroll
  for (int m = 1; m < 16; m <<= 1) {
    sx += __shfl_xor(sx, m, 64);
    sb += __shfl_xor(sb, m, 64);
  }
  if (sub == 0) {
    int h = item % H;
    float lab_c = fminf(fmaxf(l2ab[h], -3.32f), -0.015f);
    float beta  = exp2f(fminf(fmaxf(l2b[h], -2.f), 2.f));
    float ema   = sema[h] + 1e-6f;
    alpha_out[item] = alpha_formula(A[item], sx * (1.f/64.f), sb * (1.f/64.f),
                                    lab_c, beta, ema);
  }
}

__global__ __launch_bounds__(256) void scan_kernel(
    const float* __restrict__ X, const float* __restrict__ Bm,
    const float* __restrict__ Cm, const float* __restrict__ alpha_in,
    float* __restrict__ Y, int Ln, int H) {
  int bh = blockIdx.x;
  int b = bh / H, h = bh % H;
  int tid = threadIdx.x;
  int d = tid & 63, w = tid >> 6;
  const size_t rowstride = (size_t)H * 64;
  const size_t base = ((size_t)b * Ln * H + h) * 64;
  const size_t abase = (size_t)b * Ln * H + h;
  __shared__ float xb[2][64], bb2[2][64], cb[2][64], ab_s[2];
  __shared__ float red[2][4][64];
  float hreg[16];
  #pragma unroll
  for (int k = 0; k < 16; ++k) hreg[k] = 0.0f;
  if (w == 0)      xb[0][d]  = X[base + d];
  else if (w == 1) bb2[0][d] = Bm[base + d];
  else if (w == 2) cb[0][d]  = Cm[base + d];
  else if (d == 0) ab_s[0]   = alpha_in[abase];
  __syncthreads();
  for (int t = 0; t < Ln; ++t) {
    const int cur = t & 1, nxt = cur ^ 1;
    float regn = 0.0f;
    if (t + 1 < Ln) {
      size_t off = base + (size_t)(t + 1) * rowstride + d;
      if (w == 0)      regn = X[off];
      else if (w == 1) regn = Bm[off];
      else if (w == 2) regn = Cm[off];
      else if (d == 0) regn = alpha_in[abase + (size_t)(t + 1) * H];
    }
    float al = ab_s[cur];
    float xv = xb[cur][d];
    float t1 = (1.0f - al) * xv;
    float p = 0.0f;
    const float4* bp = (const float4*)&bb2[cur][w * 16];
    const float4* cp = (const float4*)&cb[cur][w * 16];
    #pragma unroll
    for (int k4 = 0; k4 < 4; ++k4) {
      float4 b4 = bp[k4]; float4 c4 = cp[k4];
      hreg[k4*4+0] = al * hreg[k4*4+0] + b4.x * t1;  p += c4.x * hreg[k4*4+0];
      hreg[k4*4+1] = al * hreg[k4*4+1] + b4.y * t1;  p += c4.y * hreg[k4*4+1];
      hreg[k4*4+2] = al * hreg[k4*4+2] + b4.z * t1;  p += c4.z * hreg[k4*4+2];
      hreg[k4*4+3] = al * hreg[k4*4+3] + b4.w * t1;  p += c4.w * hreg[k4*4+3];
    }
    red[cur][w][d] = p;
    if (t + 1 < Ln) {
      if (w == 0)      xb[nxt][d]  = regn;
      else if (w == 1) bb2[nxt][d] = regn;
      else if (w == 2) cb[nxt][d]  = regn;
      else if (d == 0) ab_s[nxt]   = regn;
    }
    __syncthreads();
    if (w == 0) {
      float y = red[cur][0][d] + red[cur][1][d] + red[cur][2][d] + red[cur][3][d];
      Y[base + (size_t)t * rowstride + d] = y;
    }
  }
}

extern "C" void kernel_launch(void* const* d_in, const int* in_sizes, int n_in,
                              void* d_out, int out_size, void* d_ws, size_t ws_size,
                              hipStream_t stream) {
  const float* X    = (const float*)d_in[0];
  const float* A    = (const float*)d_in[1];
  const float* Bm   = (const float*)d_in[2];
  const float* Cm   = (const float*)d_in[3];
  const float* l2ab = (const float*)d_in[4];
  const float* l2b  = (const float*)d_in[5];
  const float* sema = (const float*)d_in[6];
  float* Y = (float*)d_out;
  char* wsb = (char*)d_ws;

  if (ws_size >= WS_BYTES) {
    unsigned short* Sp   = (unsigned short*)(wsb + S_OFF);
    unsigned short* H0   = (unsigned short*)(wsb + H0_OFF);
    float* lamp          = (float*)(wsb + LAM_OFF);
    float* clsp          = (float*)(wsb + CLS_OFF);
    float* onemp         = (float*)(wsb + ONEM_OFF);
    phase1<<<BH * NC, 256, 0, stream>>>(X, A, Bm, l2ab, l2b, sema,
                                        Sp, lamp, clsp, onemp);
    phase2<<<(BH * 2048) / 256, 256, 0, stream>>>((const unsigned int*)Sp, lamp,
                                                  (unsigned int*)H0);
    phase3<<<BH * NC, 256, 0, stream>>>(X, Bm, Cm, H0, clsp, onemp, Y);
  } else {
    const int total = BATCH * L * NH;
    alpha_kernel<<<(total * 16) / 256, 256, 0, stream>>>(X, A, Bm, l2ab, l2b,
                                                         sema, (float*)wsb, total, NH);
    scan_kernel<<<BH, 256, 0, stream>>>(X, Bm, Cm, (float*)wsb, Y, L, NH);
  }
}

// Round 6
// 56.550 us; speedup vs baseline: 49.1952x; 1.0257x over previous
//
#include <hip/hip_runtime.h>
#include <hip/hip_bf16.h>
#include <math.h>

constexpr int BATCH = 2, L = 4096, NH = 16;
constexpr int T = 64;              // chunk length
constexpr int NC = L / T;          // 64 chunks
constexpr int BH = BATCH * NH;     // 32 chains

// ws layout (bytes)
constexpr size_t S_OFF    = 0;                                   // bf16 [BH][NC][64*64] (S^T: [d][s])
constexpr size_t S_BYTES  = (size_t)BH * NC * 4096 * 2;
constexpr size_t H0_OFF   = S_OFF + S_BYTES;                     // bf16 [BH][NC][64*64] ([d][s])
constexpr size_t H0_BYTES = (size_t)BH * NC * 4096 * 2;
constexpr size_t LAM_OFF  = H0_OFF + H0_BYTES;                   // f32 [BH][NC]
constexpr size_t LAM_BYTES = (size_t)BH * NC * 4;
constexpr size_t CLS_OFF  = LAM_OFF + LAM_BYTES;                 // f32 [BH][NC][T]
constexpr size_t CLS_BYTES = (size_t)BH * NC * T * 4;
constexpr size_t ONEM_OFF = CLS_OFF + CLS_BYTES;                 // f32 [BH][NC][T]
constexpr size_t WS_BYTES = ONEM_OFF + CLS_BYTES;

typedef __attribute__((ext_vector_type(8))) short short8;
typedef __attribute__((ext_vector_type(4))) float f32x4;
typedef __attribute__((ext_vector_type(4))) unsigned int uint4v;

// f32 -> bf16 via compiler cvt path (v_cvt_pk_bf16_f32 on gfx950), RTNE
__device__ __forceinline__ unsigned short f2bf(float f) {
  union { __hip_bfloat16 h; unsigned short u; } v;
  v.h = __float2bfloat16(f);
  return v.u;
}
__device__ __forceinline__ unsigned int pk2(float a, float b) {
  union { __hip_bfloat162 h; unsigned int u; } v;
  v.h = __float22bfloat162_rn(make_float2(a, b));
  return v.u;
}
__device__ __forceinline__ float bf2f(unsigned short u) {
  union { unsigned u; float f; } v; v.u = (unsigned)u << 16;
  return v.f;
}

// swizzled u16 index into a [64][64] bf16 LDS tile (16B-granular XOR swizzle)
__device__ __forceinline__ int swz(int row, int col) {
  return row * 64 + (col ^ ((row & 7) << 3));
}

__device__ __forceinline__ float alpha_formula(float Aval, float xbar, float bsq,
                                               float lab_c, float beta, float ema) {
  float ad = expf(Aval);
  float ab = 1.f - exp2f(lab_c);
  float om = 1.f - ad;
  float ns = om * om * xbar * xbar * bsq / ema;
  float boost = fmaxf(tanhf(beta * ns), 0.f);
  return fminf(fmaxf(ab + (1.f - ab) * boost, 0.01f), 0.999f);
}

// ---------------------------------------------------------------------------
// Phase 1 (MFMA): per (bh, chunk): alpha/cls/coeff;
//   S^T[d][s] = sum_j X[j][d] coeff[j] B[j][s]   (stored bf16, LDS-repacked)
// ---------------------------------------------------------------------------
__global__ __launch_bounds__(256) void phase1(
    const float* __restrict__ X, const float* __restrict__ A,
    const float* __restrict__ Bm,
    const float* __restrict__ l2ab, const float* __restrict__ l2b,
    const float* __restrict__ sema,
    unsigned short* __restrict__ Sp, float* __restrict__ lamp,
    float* __restrict__ clsp, float* __restrict__ onemp) {
  const int bid = blockIdx.x;                 // bh*NC + c
  const int bh = bid >> 6, c = bid & 63;
  const int b = bh >> 4, h = bh & 15;
  const int tid = threadIdx.x;
  const int r = tid >> 2, q = tid & 3;        // row j=r, col-quarter q

  __shared__ unsigned short Xt[64 * 64];      // X^T [d][j]  bf16 swizzled; later S repack
  __shared__ unsigned short Bt[64 * 64];      // (coeff B)^T [s][j] bf16 swizzled
  __shared__ float xb_s[T], bq_s[T], coeff_s[T];

  const size_t g0 = ((size_t)(b * L + c * T) * NH + h) * 64;
  const size_t grow = g0 + (size_t)r * (NH * 64);

  float xr[16], br[16];
  #pragma unroll
  for (int i = 0; i < 4; ++i) {
    *(float4*)&xr[i * 4] = *(const float4*)(X + grow + q * 16 + i * 4);
    *(float4*)&br[i * 4] = *(const float4*)(Bm + grow + q * 16 + i * 4);
  }
  float sx = 0.f, sb = 0.f;
  #pragma unroll
  for (int i = 0; i < 16; ++i) { sx += xr[i]; sb += br[i] * br[i]; }
  sx += __shfl_xor(sx, 1, 64); sx += __shfl_xor(sx, 2, 64);
  sb += __shfl_xor(sb, 1, 64); sb += __shfl_xor(sb, 2, 64);
  if (q == 0) { xb_s[r] = sx * (1.f / 64.f); bq_s[r] = sb * (1.f / 64.f); }

  // stage X^T (scatter transpose)
  #pragma unroll
  for (int i = 0; i < 16; ++i)
    Xt[swz(q * 16 + i, r)] = f2bf(xr[i]);
  __syncthreads();

  if (tid < 64) {
    float lab_c = fminf(fmaxf(l2ab[h], -3.32f), -0.015f);
    float beta  = exp2f(fminf(fmaxf(l2b[h], -2.f), 2.f));
    float ema   = sema[h] + 1e-6f;
    float Aval  = A[(size_t)(b * L + c * T + tid) * NH + h];
    float al = alpha_formula(Aval, xb_s[tid], bq_s[tid], lab_c, beta, ema);
    float onem = 1.f - al;
    float cls = logf(al);
    #pragma unroll
    for (int off = 1; off < 64; off <<= 1) {
      float o = __shfl_up(cls, off, 64);
      if (tid >= off) cls += o;
    }
    float cls63 = __shfl(cls, 63, 64);
    coeff_s[tid] = expf(cls63 - cls) * onem;
    size_t cb = (size_t)bid * T;
    clsp[cb + tid]  = cls;
    onemp[cb + tid] = onem;
    if (tid == 63) lamp[bid] = expf(cls63);
  }
  __syncthreads();

  // stage (coeff * B)^T (scatter transpose)
  {
    float cf = coeff_s[r];
    #pragma unroll
    for (int i = 0; i < 16; ++i)
      Bt[swz(q * 16 + i, r)] = f2bf(cf * br[i]);
  }
  __syncthreads();

  // MFMA: S^T[d][s]; wave w owns d-rows [16w, 16w+16)
  const int l = tid & 63, w = tid >> 6;
  const int tr = w * 16, lr = l & 15, kg = l >> 4;
  short8 aX0 = *(const short8*)&Xt[swz(tr + lr,      kg * 8)];
  short8 aX1 = *(const short8*)&Xt[swz(tr + lr, 32 + kg * 8)];
  f32x4 acc[4];
  #pragma unroll
  for (int nt = 0; nt < 4; ++nt) { acc[nt][0]=0.f; acc[nt][1]=0.f; acc[nt][2]=0.f; acc[nt][3]=0.f; }
  #pragma unroll
  for (int nt = 0; nt < 4; ++nt) {
    short8 f0 = *(const short8*)&Bt[swz(nt * 16 + lr,      kg * 8)];
    short8 f1 = *(const short8*)&Bt[swz(nt * 16 + lr, 32 + kg * 8)];
    acc[nt] = __builtin_amdgcn_mfma_f32_16x16x32_bf16(aX0, f0, acc[nt], 0, 0, 0);
    acc[nt] = __builtin_amdgcn_mfma_f32_16x16x32_bf16(aX1, f1, acc[nt], 0, 0, 0);
  }

  __syncthreads();   // all Xt/Bt fragment reads complete; Xt reusable
  // repack S (bf16) into LDS, swizzled; rows d, cols s
  #pragma unroll
  for (int nt = 0; nt < 4; ++nt)
    #pragma unroll
    for (int reg = 0; reg < 4; ++reg)
      Xt[swz(tr + kg * 4 + reg, nt * 16 + lr)] = f2bf(acc[nt][reg]);
  __syncthreads();

  // coalesced copy-out: 512 short8 groups; thread handles groups tid and 256+tid
  unsigned short* Sb = Sp + (size_t)bid * 4096;
  #pragma unroll
  for (int g2 = 0; g2 < 2; ++g2) {
    int g = g2 * 256 + tid;        // 0..511
    int row = g >> 3, c8 = (g & 7) * 8;
    short8 v = *(const short8*)&Xt[swz(row, c8)];
    *(short8*)(Sb + row * 64 + c8) = v;
  }
}

// ---------------------------------------------------------------------------
// Phase 2: exclusive chunk-scan; reads S (bf16), writes h0 (bf16).
// Recurrence stays in f32 registers; rounding is I/O-only. Deep unroll keeps
// ~16 loads in flight per thread (only 2 waves/SIMD available here).
// ---------------------------------------------------------------------------
__global__ __launch_bounds__(256) void phase2(
    const unsigned int* __restrict__ Sp, const float* __restrict__ lamp,
    unsigned int* __restrict__ H0) {
  const int gtid = blockIdx.x * 256 + threadIdx.x;   // BH*2048 threads
  const int bh = gtid >> 11;
  const int e2 = gtid & 2047;                        // u32 (pair) index in chunk
  const float* lam = lamp + (size_t)bh * NC;
  const size_t base = (size_t)bh * NC * 2048 + e2;   // u32 units
  float h0v = 0.f, h1v = 0.f;
  #pragma unroll 16
  for (int c = 0; c < NC; ++c) {
    size_t off = base + (size_t)c * 2048;
    unsigned v = Sp[off];
    H0[off] = pk2(h0v, h1v);
    float la = lam[c];
    h0v = la * h0v + bf2f((unsigned short)(v & 0xFFFFu));
    h1v = la * h1v + bf2f((unsigned short)(v >> 16));
  }
}

// ---------------------------------------------------------------------------
// Phase 3 (MFMA): Y = diag(e^cls) (C @ h0) + (W ⊙ (C @ B^T)) @ X
// ---------------------------------------------------------------------------
__global__ __launch_bounds__(256) void phase3(
    const float* __restrict__ X, const float* __restrict__ Bm,
    const float* __restrict__ Cm, const unsigned short* __restrict__ H0,
    const float* __restrict__ clsp, const float* __restrict__ onemp,
    float* __restrict__ Y) {
  const int bid = blockIdx.x;
  const int bh = bid >> 6, c = bid & 63;
  const int b = bh >> 4, h = bh & 15;
  const int tid = threadIdx.x;
  const int l = tid & 63, w = tid >> 6;

  __shared__ unsigned short Cl[64 * 64];  // C  [t][s]  (A-op)
  __shared__ unsigned short Bl[64 * 64];  // B  [j][s]  (B-op of C B^T)
  __shared__ unsigned short Hl[64 * 64];  // h0^T [d][s]; later WG [t][j]
  __shared__ unsigned short Xt[64 * 64];  // X^T [d][j]
  __shared__ float cl2_s[64], onem_s[64], ecls_s[64];

  const size_t g0 = ((size_t)(b * L + c * T) * NH + h) * 64;
  const int r = tid >> 2, q = tid & 3;
  const size_t grow = g0 + (size_t)r * (NH * 64);
  const unsigned short* h0p = H0 + (size_t)bid * 4096;

  #pragma unroll
  for (int i = 0; i < 2; ++i) {
    int col = q * 16 + i * 8;
    float4 c0 = *(const float4*)(Cm + grow + col);
    float4 c1 = *(const float4*)(Cm + grow + col + 4);
    float4 b0 = *(const float4*)(Bm + grow + col);
    float4 b1 = *(const float4*)(Bm + grow + col + 4);
    float4 x0 = *(const float4*)(X + grow + col);
    float4 x1 = *(const float4*)(X + grow + col + 4);
    short8 hv = *(const short8*)(h0p + (size_t)r * 64 + col);   // bf16 direct
    int o = swz(r, col);
    uint4v cv = { pk2(c0.x, c0.y), pk2(c0.z, c0.w), pk2(c1.x, c1.y), pk2(c1.z, c1.w) };
    uint4v bv = { pk2(b0.x, b0.y), pk2(b0.z, b0.w), pk2(b1.x, b1.y), pk2(b1.z, b1.w) };
    *(uint4v*)&Cl[o] = cv;
    *(uint4v*)&Bl[o] = bv;
    *(short8*)&Hl[o] = hv;
    float xs[8] = {x0.x, x0.y, x0.z, x0.w, x1.x, x1.y, x1.z, x1.w};
    #pragma unroll
    for (int ii = 0; ii < 8; ++ii)
      Xt[swz(col + ii, r)] = f2bf(xs[ii]);
  }
  if (tid < 64) {
    float cls = clsp[(size_t)bid * T + tid];
    cl2_s[tid]  = cls * 1.44269504088896f;
    ecls_s[tid] = expf(cls);
    onem_s[tid] = onemp[(size_t)bid * T + tid];
  }
  __syncthreads();

  const int tr = w * 16, lr = l & 15, kg = l >> 4;

  short8 aC0 = *(const short8*)&Cl[swz(tr + lr,      kg * 8)];
  short8 aC1 = *(const short8*)&Cl[swz(tr + lr, 32 + kg * 8)];

  // matmul1: Z = C @ h0
  f32x4 acc[4];
  #pragma unroll
  for (int nt = 0; nt < 4; ++nt) { acc[nt][0]=0.f; acc[nt][1]=0.f; acc[nt][2]=0.f; acc[nt][3]=0.f; }
  #pragma unroll
  for (int nt = 0; nt < 4; ++nt) {
    short8 f0 = *(const short8*)&Hl[swz(nt * 16 + lr,      kg * 8)];
    short8 f1 = *(const short8*)&Hl[swz(nt * 16 + lr, 32 + kg * 8)];
    acc[nt] = __builtin_amdgcn_mfma_f32_16x16x32_bf16(aC0, f0, acc[nt], 0, 0, 0);
    acc[nt] = __builtin_amdgcn_mfma_f32_16x16x32_bf16(aC1, f1, acc[nt], 0, 0, 0);
  }
  float e0 = ecls_s[tr + kg * 4 + 0], e1 = ecls_s[tr + kg * 4 + 1];
  float e2 = ecls_s[tr + kg * 4 + 2], e3 = ecls_s[tr + kg * 4 + 3];
  #pragma unroll
  for (int nt = 0; nt < 4; ++nt) {
    acc[nt][0] *= e0; acc[nt][1] *= e1; acc[nt][2] *= e2; acc[nt][3] *= e3;
  }

  // matmul2: G = C @ B^T
  f32x4 g[4];
  #pragma unroll
  for (int nt = 0; nt < 4; ++nt) { g[nt][0]=0.f; g[nt][1]=0.f; g[nt][2]=0.f; g[nt][3]=0.f; }
  #pragma unroll
  for (int nt = 0; nt < 4; ++nt) {
    short8 f0 = *(const short8*)&Bl[swz(nt * 16 + lr,      kg * 8)];
    short8 f1 = *(const short8*)&Bl[swz(nt * 16 + lr, 32 + kg * 8)];
    g[nt] = __builtin_amdgcn_mfma_f32_16x16x32_bf16(aC0, f0, g[nt], 0, 0, 0);
    g[nt] = __builtin_amdgcn_mfma_f32_16x16x32_bf16(aC1, f1, g[nt], 0, 0, 0);
  }
  float c2r[4] = {cl2_s[tr + kg * 4 + 0], cl2_s[tr + kg * 4 + 1],
                  cl2_s[tr + kg * 4 + 2], cl2_s[tr + kg * 4 + 3]};
  #pragma unroll
  for (int nt = 0; nt < 4; ++nt) {
    int j = nt * 16 + lr;
    float c2j = cl2_s[j], om = onem_s[j];
    #pragma unroll
    for (int reg = 0; reg < 4; ++reg) {
      int t = tr + kg * 4 + reg;
      float wgt = (t >= j) ? exp2f(c2r[reg] - c2j) * om : 0.f;
      g[nt][reg] *= wgt;
    }
  }
  __syncthreads();

  #pragma unroll
  for (int nt = 0; nt < 4; ++nt)
    #pragma unroll
    for (int reg = 0; reg < 4; ++reg)
      Hl[swz(tr + kg * 4 + reg, nt * 16 + lr)] = f2bf(g[nt][reg]);
  __syncthreads();

  // matmul3: Y += WG @ X
  short8 aW0 = *(const short8*)&Hl[swz(tr + lr,      kg * 8)];
  short8 aW1 = *(const short8*)&Hl[swz(tr + lr, 32 + kg * 8)];
  #pragma unroll
  for (int nt = 0; nt < 4; ++nt) {
    short8 f0 = *(const short8*)&Xt[swz(nt * 16 + lr,      kg * 8)];
    short8 f1 = *(const short8*)&Xt[swz(nt * 16 + lr, 32 + kg * 8)];
    acc[nt] = __builtin_amdgcn_mfma_f32_16x16x32_bf16(aW0, f0, acc[nt], 0, 0, 0);
    acc[nt] = __builtin_amdgcn_mfma_f32_16x16x32_bf16(aW1, f1, acc[nt], 0, 0, 0);
  }

  #pragma unroll
  for (int reg = 0; reg < 4; ++reg) {
    int t = tr + kg * 4 + reg;
    #pragma unroll
    for (int nt = 0; nt < 4; ++nt)
      Y[g0 + (size_t)t * (NH * 64) + nt * 16 + lr] = acc[nt][reg];
  }
}

// ---------------------------------------------------------------------------
// Fallback (round-1) path if ws is too small
// ---------------------------------------------------------------------------
__global__ __launch_bounds__(256) void alpha_kernel(
    const float* __restrict__ X, const float* __restrict__ A,
    const float* __restrict__ Bm,
    const float* __restrict__ l2ab, const float* __restrict__ l2b,
    const float* __restrict__ sema,
    float* __restrict__ alpha_out, int total, int H) {
  int tid = blockIdx.x * 256 + threadIdx.x;
  int item = tid >> 4, sub = tid & 15;
  if (item >= total) return;
  const float4 xv = *(const float4*)(X + (size_t)item * 64 + sub * 4);
  const float4 bv = *(const float4*)(Bm + (size_t)item * 64 + sub * 4);
  float sx = xv.x + xv.y + xv.z + xv.w;
  float sb = bv.x * bv.x + bv.y * bv.y + bv.z * bv.z + bv.w * bv.w;
  #pragma unroll
  for (int m = 1; m < 16; m <<= 1) {
    sx += __shfl_xor(sx, m, 64);
    sb += __shfl_xor(sb, m, 64);
  }
  if (sub == 0) {
    int h = item % H;
    float lab_c = fminf(fmaxf(l2ab[h], -3.32f), -0.015f);
    float beta  = exp2f(fminf(fmaxf(l2b[h], -2.f), 2.f));
    float ema   = sema[h] + 1e-6f;
    alpha_out[item] = alpha_formula(A[item], sx * (1.f/64.f), sb * (1.f/64.f),
                                    lab_c, beta, ema);
  }
}

__global__ __launch_bounds__(256) void scan_kernel(
    const float* __restrict__ X, const float* __restrict__ Bm,
    const float* __restrict__ Cm, const float* __restrict__ alpha_in,
    float* __restrict__ Y, int Ln, int H) {
  int bh = blockIdx.x;
  int b = bh / H, h = bh % H;
  int tid = threadIdx.x;
  int d = tid & 63, w = tid >> 6;
  const size_t rowstride = (size_t)H * 64;
  const size_t base = ((size_t)b * Ln * H + h) * 64;
  const size_t abase = (size_t)b * Ln * H + h;
  __shared__ float xb[2][64], bb2[2][64], cb[2][64], ab_s[2];
  __shared__ float red[2][4][64];
  float hreg[16];
  #pragma unroll
  for (int k = 0; k < 16; ++k) hreg[k] = 0.0f;
  if (w == 0)      xb[0][d]  = X[base + d];
  else if (w == 1) bb2[0][d] = Bm[base + d];
  else if (w == 2) cb[0][d]  = Cm[base + d];
  else if (d == 0) ab_s[0]   = alpha_in[abase];
  __syncthreads();
  for (int t = 0; t < Ln; ++t) {
    const int cur = t & 1, nxt = cur ^ 1;
    float regn = 0.0f;
    if (t + 1 < Ln) {
      size_t off = base + (size_t)(t + 1) * rowstride + d;
      if (w == 0)      regn = X[off];
      else if (w == 1) regn = Bm[off];
      else if (w == 2) regn = Cm[off];
      else if (d == 0) regn = alpha_in[abase + (size_t)(t + 1) * H];
    }
    float al = ab_s[cur];
    float xv = xb[cur][d];
    float t1 = (1.0f - al) * xv;
    float p = 0.0f;
    const float4* bp = (const float4*)&bb2[cur][w * 16];
    const float4* cp = (const float4*)&cb[cur][w * 16];
    #pragma unroll
    for (int k4 = 0; k4 < 4; ++k4) {
      float4 b4 = bp[k4]; float4 c4 = cp[k4];
      hreg[k4*4+0] = al * hreg[k4*4+0] + b4.x * t1;  p += c4.x * hreg[k4*4+0];
      hreg[k4*4+1] = al * hreg[k4*4+1] + b4.y * t1;  p += c4.y * hreg[k4*4+1];
      hreg[k4*4+2] = al * hreg[k4*4+2] + b4.z * t1;  p += c4.z * hreg[k4*4+2];
      hreg[k4*4+3] = al * hreg[k4*4+3] + b4.w * t1;  p += c4.w * hreg[k4*4+3];
    }
    red[cur][w][d] = p;
    if (t + 1 < Ln) {
      if (w == 0)      xb[nxt][d]  = regn;
      else if (w == 1) bb2[nxt][d] = regn;
      else if (w == 2) cb[nxt][d]  = regn;
      else if (d == 0) ab_s[nxt]   = regn;
    }
    __syncthreads();
    if (w == 0) {
      float y = red[cur][0][d] + red[cur][1][d] + red[cur][2][d] + red[cur][3][d];
      Y[base + (size_t)t * rowstride + d] = y;
    }
  }
}

extern "C" void kernel_launch(void* const* d_in, const int* in_sizes, int n_in,
                              void* d_out, int out_size, void* d_ws, size_t ws_size,
                              hipStream_t stream) {
  const float* X    = (const float*)d_in[0];
  const float* A    = (const float*)d_in[1];
  const float* Bm   = (const float*)d_in[2];
  const float* Cm   = (const float*)d_in[3];
  const float* l2ab = (const float*)d_in[4];
  const float* l2b  = (const float*)d_in[5];
  const float* sema = (const float*)d_in[6];
  float* Y = (float*)d_out;
  char* wsb = (char*)d_ws;

  if (ws_size >= WS_BYTES) {
    unsigned short* Sp   = (unsigned short*)(wsb + S_OFF);
    unsigned short* H0   = (unsigned short*)(wsb + H0_OFF);
    float* lamp          = (float*)(wsb + LAM_OFF);
    float* clsp          = (float*)(wsb + CLS_OFF);
    float* onemp         = (float*)(wsb + ONEM_OFF);
    phase1<<<BH * NC, 256, 0, stream>>>(X, A, Bm, l2ab, l2b, sema,
                                        Sp, lamp, clsp, onemp);
    phase2<<<(BH * 2048) / 256, 256, 0, stream>>>((const unsigned int*)Sp, lamp,
                                                  (unsigned int*)H0);
    phase3<<<BH * NC, 256, 0, stream>>>(X, Bm, Cm, H0, clsp, onemp, Y);
  } else {
    const int total = BATCH * L * NH;
    alpha_kernel<<<(total * 16) / 256, 256, 0, stream>>>(X, A, Bm, l2ab, l2b,
                                                         sema, (float*)wsb, total, NH);
    scan_kernel<<<BH, 256, 0, stream>>>(X, Bm, Cm, (float*)wsb, Y, L, NH);
  }
}